// Round 13
// baseline (277.177 us; speedup 1.0000x reference)
//
#include <hip/hip_runtime.h>
#include <stdint.h>

// Round 13: (a) proj & FF2 moved to gemm128_kernel — an 8-phase 128x128
// port of the proven gemm256 schedule (512 thr, 8 waves 2Mx4N, 64 KiB
// double-buffered LDS, same barrier/vmcnt/lgkmcnt pattern); their N=1024
// shape gives 256 blocks = 1/CU where 8-phase self-hiding beats m97.
// (b) attn (round-8 base) + T13 defer-max: skip corr/oacc rescale unless
// __any(pm > mrow+12). QKV/FF1/LN/transposes frozen from round 12.

typedef unsigned short u16;
typedef unsigned int u32;
typedef __attribute__((ext_vector_type(4))) float f32x4;
typedef __attribute__((ext_vector_type(8))) short s16x8;

__device__ __forceinline__ u16 f2bf(float f) {
  u32 u = __builtin_bit_cast(u32, f);
  u += 0x7fffu + ((u >> 16) & 1u);
  return (u16)(u >> 16);
}
// 8-byte-aligned s16x8 load (2 x b64) for odd-stride LDS rows
__device__ __forceinline__ s16x8 ld_s16x8_a8(const u16* p) {
  union { uint2 d[2]; s16x8 v; } u;
  u.d[0] = *(const uint2*)p;
  u.d[1] = *(const uint2*)(p + 4);
  return u.v;
}
// async global->LDS, 16B per lane; lds dest must be wave-uniform base
__device__ __forceinline__ void gload16(const u16* g, u16* lds_base) {
  __builtin_amdgcn_global_load_lds(
      (const __attribute__((address_space(1))) void*)g,
      (__attribute__((address_space(3))) void*)lds_base, 16, 0, 0);
}

// ---------------------------------------------------------------------------
// Tiled transpose fp32 -> bf16: dst[(c)*dstStride + r] = src[r*Ccols + c]
// ---------------------------------------------------------------------------
__global__ __launch_bounds__(256) void transpose_f32_bf16(
    const float* __restrict__ src, u16* __restrict__ dst,
    int Ccols, long srcZ, long dstZ, int dstStride) {
  __shared__ float t[64][65];
  const float* s = src + (size_t)blockIdx.z * srcZ;
  u16* d = dst + (size_t)blockIdx.z * dstZ;
  const int r0 = blockIdx.y * 64, c0 = blockIdx.x * 64;
  const int tr = threadIdx.x >> 4, tc4 = (threadIdx.x & 15) * 4;
#pragma unroll
  for (int p = 0; p < 4; ++p) {
    int r = p * 16 + tr;
    float4 v = *(const float4*)(s + (size_t)(r0 + r) * Ccols + c0 + tc4);
    t[r][tc4 + 0] = v.x; t[r][tc4 + 1] = v.y;
    t[r][tc4 + 2] = v.z; t[r][tc4 + 3] = v.w;
  }
  __syncthreads();
#pragma unroll
  for (int p = 0; p < 4; ++p) {
    int c = p * 16 + tr;
    uint2 pk;
    pk.x = (u32)f2bf(t[tc4 + 0][c]) | ((u32)f2bf(t[tc4 + 1][c]) << 16);
    pk.y = (u32)f2bf(t[tc4 + 2][c]) | ((u32)f2bf(t[tc4 + 3][c]) << 16);
    *(uint2*)(d + (size_t)(c0 + c) * dstStride + r0 + tc4) = pk;
  }
}

// ---------------------------------------------------------------------------
// LayerNorm: one block per row of 1024 fp32; out bf16.
// ---------------------------------------------------------------------------
__global__ __launch_bounds__(256) void ln_kernel(
    const float* __restrict__ x, const float* __restrict__ g,
    const float* __restrict__ be, u16* __restrict__ out) {
  const int row = blockIdx.x, tid = threadIdx.x;
  const float* xr = x + (size_t)row * 1024;
  float4 v = *(const float4*)(xr + tid * 4);
  float s = v.x + v.y + v.z + v.w;
  float q = v.x * v.x + v.y * v.y + v.z * v.z + v.w * v.w;
#pragma unroll
  for (int off = 32; off > 0; off >>= 1) {
    s += __shfl_down(s, off);
    q += __shfl_down(q, off);
  }
  __shared__ float red[8];
  const int wid = tid >> 6, lane = tid & 63;
  if (lane == 0) { red[wid] = s; red[wid + 4] = q; }
  __syncthreads();
  s = red[0] + red[1] + red[2] + red[3];
  q = red[4] + red[5] + red[6] + red[7];
  const float mu = s * (1.f / 1024.f);
  const float var = q * (1.f / 1024.f) - mu * mu;
  const float rs = rsqrtf(var + 1e-5f);
  float4 gv = *(const float4*)(g + tid * 4);
  float4 bv = *(const float4*)(be + tid * 4);
  float o0 = (v.x - mu) * rs * gv.x + bv.x;
  float o1 = (v.y - mu) * rs * gv.y + bv.y;
  float o2 = (v.z - mu) * rs * gv.z + bv.z;
  float o3 = (v.w - mu) * rs * gv.w + bv.w;
  uint2 pk;
  pk.x = (u32)f2bf(o0) | ((u32)f2bf(o1) << 16);
  pk.y = (u32)f2bf(o2) | ((u32)f2bf(o3) << 16);
  *(uint2*)(out + (size_t)row * 1024 + tid * 4) = pk;
}

// ---------------------------------------------------------------------------
// GEMM (m97): C[M,N] = A[M,K] @ BT[N,K]^T (+ bias, relu, residual per EPI)
// ---------------------------------------------------------------------------
template <int EPI, int BM>
__global__ __launch_bounds__(256) void gemm_kernel(
    const u16* __restrict__ A, const u16* __restrict__ BT,
    const float* __restrict__ bias, const float* __restrict__ resid,
    void* __restrict__ out, int M, int N, int K) {
  __shared__ u16 sA[BM][64];
  __shared__ u16 sB[128][64];
  const int tid = threadIdx.x;
  const int m0 = blockIdx.y * BM, n0 = blockIdx.x * 128;
  const int wid = tid >> 6, lane = tid & 63;
  const int wr = (wid >> 1) * (BM / 2), wc = (wid & 1) * 64;
  const int l15 = lane & 15, g = lane >> 4;
  constexpr int MR = BM / 32;
  f32x4 acc[MR][4] = {};
  const int lr = lane >> 3;
  const int cswz = ((lane & 7) * 8) ^ (lr << 3);  // u16 units

  for (int k0 = 0; k0 < K; k0 += 64) {
    __syncthreads();
#pragma unroll
    for (int p = 0; p < MR; ++p) {
      const int row = (p * 4 + wid) * 8 + lr;
      gload16(A + (size_t)(m0 + row) * K + k0 + cswz, &sA[(p * 4 + wid) * 8][0]);
    }
#pragma unroll
    for (int p = 0; p < 4; ++p) {
      const int row = (p * 4 + wid) * 8 + lr;
      gload16(BT + (size_t)(n0 + row) * K + k0 + cswz, &sB[(p * 4 + wid) * 8][0]);
    }
    __syncthreads();
#pragma unroll
    for (int kk = 0; kk < 64; kk += 32) {
      s16x8 af[MR], bf[4];
#pragma unroll
      for (int m = 0; m < MR; ++m) {
        const int R = wr + m * 16 + l15;
        af[m] = *(const s16x8*)(&sA[R][(kk + g * 8) ^ ((R & 7) << 3)]);
      }
#pragma unroll
      for (int n = 0; n < 4; ++n) {
        const int R = wc + n * 16 + l15;
        bf[n] = *(const s16x8*)(&sB[R][(kk + g * 8) ^ ((R & 7) << 3)]);
      }
#pragma unroll
      for (int m = 0; m < MR; ++m)
#pragma unroll
        for (int n = 0; n < 4; ++n)
          acc[m][n] = __builtin_amdgcn_mfma_f32_16x16x32_bf16(af[m], bf[n], acc[m][n], 0, 0, 0);
    }
  }

#pragma unroll
  for (int m = 0; m < MR; ++m) {
#pragma unroll
    for (int n = 0; n < 4; ++n) {
      const int col = n0 + wc + n * 16 + l15;
      float bv = 0.f;
      if (EPI >= 1) bv = bias[col];
#pragma unroll
      for (int i = 0; i < 4; ++i) {
        const int row = m0 + wr + m * 16 + g * 4 + i;
        float v = acc[m][n][i];
        if (EPI >= 1) v += bv;
        if (EPI == 1) v = fmaxf(v, 0.f);
        if (EPI == 2) {
          v += resid[(size_t)row * N + col];
          ((float*)out)[(size_t)row * N + col] = v;
        } else {
          ((u16*)out)[(size_t)row * N + col] = f2bf(v);
        }
      }
    }
  }
}

// ---------------------------------------------------------------------------
// 256x256 8-phase GEMM (T3+T4+T5) — FF1. See round-12 notes.
// ---------------------------------------------------------------------------
template <int EPI>
__global__ __launch_bounds__(512, 2) void gemm256_kernel(
    const u16* __restrict__ A, const u16* __restrict__ BT,
    const float* __restrict__ bias, const float* __restrict__ resid,
    void* __restrict__ out, int M, int N, int K) {
  __shared__ u16 lds[2][2][256][64];  // 128 KiB
  const int tid = threadIdx.x;
  const int wid = tid >> 6, lane = tid & 63;
  const int m0 = blockIdx.y * 256, n0 = blockIdx.x * 256;
  const int wr = (wid >> 2) * 128;
  const int wc = (wid & 3) * 64;
  const int l15 = lane & 15, g = lane >> 4;
  const int lr = lane >> 3;
  const int cswz = ((lane & 7) * 8) ^ (lr << 3);
  const int swz = (l15 & 7) << 3;
  const u16* Abase = A + (size_t)m0 * K;
  const u16* Bbase = BT + (size_t)n0 * K;
  const int nkt = K >> 6;

  f32x4 acc[8][4] = {};
  s16x8 bf[4][2];

  auto issue_half = [&](const u16* Xbase, int xi, int t, int hf) {
    const int b = t & 1;
    const int r0 = hf * 128 + wid * 8;
    gload16(Xbase + (size_t)(r0 + lr) * K + t * 64 + cswz, &lds[b][xi][r0][0]);
    gload16(Xbase + (size_t)(r0 + 64 + lr) * K + t * 64 + cswz, &lds[b][xi][r0 + 64][0]);
  };

  issue_half(Abase, 0, 0, 0);
  issue_half(Abase, 0, 0, 1);
  issue_half(Bbase, 1, 0, 0);
  issue_half(Bbase, 1, 0, 1);
  asm volatile("s_waitcnt vmcnt(0)" ::: "memory");
  __builtin_amdgcn_s_barrier();

  for (int i = 0; i < nkt; i += 2) {
#pragma unroll
    for (int p = 0; p < 4; ++p) {
      s16x8 af[2][2];
#pragma unroll
      for (int q = 0; q < 2; ++q) {
        const int R = wr + (2 * p + q) * 16 + l15;
#pragma unroll
        for (int h = 0; h < 2; ++h)
          af[q][h] = *(const s16x8*)(&lds[0][0][R][(h * 32 + g * 8) ^ swz]);
      }
      if (p == 0) {
#pragma unroll
        for (int n = 0; n < 4; ++n) {
          const int R = wc + n * 16 + l15;
#pragma unroll
          for (int h = 0; h < 2; ++h)
            bf[n][h] = *(const s16x8*)(&lds[0][1][R][(h * 32 + g * 8) ^ swz]);
        }
      }
      if (i + 1 < nkt) {
        if (p == 0) issue_half(Abase, 0, i + 1, 0);
        else if (p == 1) issue_half(Abase, 0, i + 1, 1);
        else if (p == 2) issue_half(Bbase, 1, i + 1, 0);
        else issue_half(Bbase, 1, i + 1, 1);
      }
      __builtin_amdgcn_s_barrier();
      asm volatile("s_waitcnt lgkmcnt(0)" ::: "memory");
      __builtin_amdgcn_sched_barrier(0);
      __builtin_amdgcn_s_setprio(1);
#pragma unroll
      for (int q = 0; q < 2; ++q)
#pragma unroll
        for (int n = 0; n < 4; ++n) {
          acc[2 * p + q][n] = __builtin_amdgcn_mfma_f32_16x16x32_bf16(af[q][0], bf[n][0], acc[2 * p + q][n], 0, 0, 0);
          acc[2 * p + q][n] = __builtin_amdgcn_mfma_f32_16x16x32_bf16(af[q][1], bf[n][1], acc[2 * p + q][n], 0, 0, 0);
        }
      __builtin_amdgcn_s_setprio(0);
      if (p == 3)
        asm volatile("s_waitcnt vmcnt(0)" ::: "memory");
      __builtin_amdgcn_s_barrier();
    }
    if (i + 1 < nkt) {
#pragma unroll
      for (int p = 0; p < 4; ++p) {
        s16x8 af[2][2];
#pragma unroll
        for (int q = 0; q < 2; ++q) {
          const int R = wr + (2 * p + q) * 16 + l15;
#pragma unroll
          for (int h = 0; h < 2; ++h)
            af[q][h] = *(const s16x8*)(&lds[1][0][R][(h * 32 + g * 8) ^ swz]);
        }
        if (p == 0) {
#pragma unroll
          for (int n = 0; n < 4; ++n) {
            const int R = wc + n * 16 + l15;
#pragma unroll
            for (int h = 0; h < 2; ++h)
              bf[n][h] = *(const s16x8*)(&lds[1][1][R][(h * 32 + g * 8) ^ swz]);
          }
        }
        if (i + 2 < nkt) {
          if (p == 0) issue_half(Abase, 0, i + 2, 0);
          else if (p == 1) issue_half(Abase, 0, i + 2, 1);
          else if (p == 2) issue_half(Bbase, 1, i + 2, 0);
          else issue_half(Bbase, 1, i + 2, 1);
        }
        __builtin_amdgcn_s_barrier();
        asm volatile("s_waitcnt lgkmcnt(0)" ::: "memory");
        __builtin_amdgcn_sched_barrier(0);
        __builtin_amdgcn_s_setprio(1);
#pragma unroll
        for (int q = 0; q < 2; ++q)
#pragma unroll
          for (int n = 0; n < 4; ++n) {
            acc[2 * p + q][n] = __builtin_amdgcn_mfma_f32_16x16x32_bf16(af[q][0], bf[n][0], acc[2 * p + q][n], 0, 0, 0);
            acc[2 * p + q][n] = __builtin_amdgcn_mfma_f32_16x16x32_bf16(af[q][1], bf[n][1], acc[2 * p + q][n], 0, 0, 0);
          }
        __builtin_amdgcn_s_setprio(0);
        if (p == 3)
          asm volatile("s_waitcnt vmcnt(0)" ::: "memory");
        __builtin_amdgcn_s_barrier();
      }
    }
  }

#pragma unroll
  for (int mi = 0; mi < 8; ++mi)
#pragma unroll
    for (int n = 0; n < 4; ++n) {
      const int col = n0 + wc + n * 16 + l15;
      float bv = (EPI >= 1) ? bias[col] : 0.f;
#pragma unroll
      for (int ii = 0; ii < 4; ++ii) {
        const int row = m0 + wr + mi * 16 + g * 4 + ii;
        float v = acc[mi][n][ii];
        if (EPI >= 1) v += bv;
        if (EPI == 1) v = fmaxf(v, 0.f);
        ((u16*)out)[(size_t)row * N + col] = f2bf(v);
      }
    }
}

// ---------------------------------------------------------------------------
// 128x128 8-phase GEMM — same schedule as gemm256, smaller geometry.
// 512 threads = 8 waves (2M x 4N), per-wave 64x32 output; BK=64; 64 KiB LDS
// (2 dbuf x A,B x 128x64). 2 phases per K-tile (8 MFMA each), 2 K-tiles per
// iteration; vmcnt(0) only at the end of each K-tile's phase pair.
// For proj/FF2 (N=1024): grid 8x32 = 256 blocks = 1/CU.
// ---------------------------------------------------------------------------
template <int EPI>
__global__ __launch_bounds__(512, 2) void gemm128_kernel(
    const u16* __restrict__ A, const u16* __restrict__ BT,
    const float* __restrict__ bias, const float* __restrict__ resid,
    void* __restrict__ out, int M, int N, int K) {
  __shared__ u16 lds[2][2][128][64];  // 64 KiB
  const int tid = threadIdx.x;
  const int wid = tid >> 6, lane = tid & 63;
  const int m0 = blockIdx.y * 128, n0 = blockIdx.x * 128;
  const int wr = (wid >> 2) * 64;   // 2 M-wave-groups
  const int wc = (wid & 3) * 32;    // 4 N-wave-groups
  const int l15 = lane & 15, g = lane >> 4;
  const int lr = lane >> 3;
  const int cswz = ((lane & 7) * 8) ^ (lr << 3);
  const int swz = (l15 & 7) << 3;
  const u16* Abase = A + (size_t)m0 * K;
  const u16* Bbase = BT + (size_t)n0 * K;
  const int nkt = K >> 6;

  f32x4 acc[4][2] = {};
  s16x8 bf[2][2];

  // one gload per thread covers 64 rows (512 lanes x 16B = 8 KB)
  auto issue_half = [&](const u16* Xbase, int xi, int t, int hf) {
    const int b = t & 1;
    const int r0 = hf * 64 + wid * 8;
    gload16(Xbase + (size_t)(r0 + lr) * K + t * 64 + cswz, &lds[b][xi][r0][0]);
  };

  // prologue: tile 0 staged + drained
  issue_half(Abase, 0, 0, 0); issue_half(Abase, 0, 0, 1);
  issue_half(Bbase, 1, 0, 0); issue_half(Bbase, 1, 0, 1);
  asm volatile("s_waitcnt vmcnt(0)" ::: "memory");
  __builtin_amdgcn_s_barrier();

  for (int i = 0; i < nkt; i += 2) {
    // phases 0-1: consume buf0 (tile i); issue tile i+1 into buf1
#pragma unroll
    for (int p = 0; p < 2; ++p) {
      s16x8 af[2][2];
#pragma unroll
      for (int q = 0; q < 2; ++q) {
        const int R = wr + (2 * p + q) * 16 + l15;
#pragma unroll
        for (int h = 0; h < 2; ++h)
          af[q][h] = *(const s16x8*)(&lds[0][0][R][(h * 32 + g * 8) ^ swz]);
      }
      if (p == 0) {
#pragma unroll
        for (int n = 0; n < 2; ++n) {
          const int R = wc + n * 16 + l15;
#pragma unroll
          for (int h = 0; h < 2; ++h)
            bf[n][h] = *(const s16x8*)(&lds[0][1][R][(h * 32 + g * 8) ^ swz]);
        }
      }
      if (i + 1 < nkt) {
        if (p == 0) { issue_half(Abase, 0, i + 1, 0); issue_half(Abase, 0, i + 1, 1); }
        else        { issue_half(Bbase, 1, i + 1, 0); issue_half(Bbase, 1, i + 1, 1); }
      }
      __builtin_amdgcn_s_barrier();
      asm volatile("s_waitcnt lgkmcnt(0)" ::: "memory");
      __builtin_amdgcn_sched_barrier(0);
      __builtin_amdgcn_s_setprio(1);
#pragma unroll
      for (int q = 0; q < 2; ++q)
#pragma unroll
        for (int n = 0; n < 2; ++n) {
          acc[2 * p + q][n] = __builtin_amdgcn_mfma_f32_16x16x32_bf16(af[q][0], bf[n][0], acc[2 * p + q][n], 0, 0, 0);
          acc[2 * p + q][n] = __builtin_amdgcn_mfma_f32_16x16x32_bf16(af[q][1], bf[n][1], acc[2 * p + q][n], 0, 0, 0);
        }
      __builtin_amdgcn_s_setprio(0);
      if (p == 1)
        asm volatile("s_waitcnt vmcnt(0)" ::: "memory");
      __builtin_amdgcn_s_barrier();
    }
    // phases 2-3: consume buf1 (tile i+1); issue tile i+2 into buf0
    if (i + 1 < nkt) {
#pragma unroll
      for (int p = 0; p < 2; ++p) {
        s16x8 af[2][2];
#pragma unroll
        for (int q = 0; q < 2; ++q) {
          const int R = wr + (2 * p + q) * 16 + l15;
#pragma unroll
          for (int h = 0; h < 2; ++h)
            af[q][h] = *(const s16x8*)(&lds[1][0][R][(h * 32 + g * 8) ^ swz]);
        }
        if (p == 0) {
#pragma unroll
          for (int n = 0; n < 2; ++n) {
            const int R = wc + n * 16 + l15;
#pragma unroll
            for (int h = 0; h < 2; ++h)
              bf[n][h] = *(const s16x8*)(&lds[1][1][R][(h * 32 + g * 8) ^ swz]);
          }
        }
        if (i + 2 < nkt) {
          if (p == 0) { issue_half(Abase, 0, i + 2, 0); issue_half(Abase, 0, i + 2, 1); }
          else        { issue_half(Bbase, 1, i + 2, 0); issue_half(Bbase, 1, i + 2, 1); }
        }
        __builtin_amdgcn_s_barrier();
        asm volatile("s_waitcnt lgkmcnt(0)" ::: "memory");
        __builtin_amdgcn_sched_barrier(0);
        __builtin_amdgcn_s_setprio(1);
#pragma unroll
        for (int q = 0; q < 2; ++q)
#pragma unroll
          for (int n = 0; n < 2; ++n) {
            acc[2 * p + q][n] = __builtin_amdgcn_mfma_f32_16x16x32_bf16(af[q][0], bf[n][0], acc[2 * p + q][n], 0, 0, 0);
            acc[2 * p + q][n] = __builtin_amdgcn_mfma_f32_16x16x32_bf16(af[q][1], bf[n][1], acc[2 * p + q][n], 0, 0, 0);
          }
        __builtin_amdgcn_s_setprio(0);
        if (p == 1)
          asm volatile("s_waitcnt vmcnt(0)" ::: "memory");
        __builtin_amdgcn_s_barrier();
      }
    }
  }

#pragma unroll
  for (int mi = 0; mi < 4; ++mi)
#pragma unroll
    for (int n = 0; n < 2; ++n) {
      const int col = n0 + wc + n * 16 + l15;
      float bv = (EPI >= 1) ? bias[col] : 0.f;
#pragma unroll
      for (int ii = 0; ii < 4; ++ii) {
        const int row = m0 + wr + mi * 16 + g * 4 + ii;
        float v = acc[mi][n][ii];
        if (EPI >= 1) v += bv;
        if (EPI == 1) v = fmaxf(v, 0.f);
        if (EPI == 2) {
          v += resid[(size_t)row * N + col];
          ((float*)out)[(size_t)row * N + col] = v;
        } else {
          ((u16*)out)[(size_t)row * N + col] = f2bf(v);
        }
      }
    }
}

// ---------------------------------------------------------------------------
// MFMA causal flash attention (round-8 base + T13 defer-max).
// Paired q-tiles {31-bx, bx}; T14 reg-prefetch staging. grid (16, B*H), 256.
// ---------------------------------------------------------------------------
__global__ __launch_bounds__(256) void attn_mfma_kernel(
    const u16* __restrict__ qkv, u16* __restrict__ o) {
  __shared__ u16 sK[64][72];    // [s][d]
  __shared__ u16 sVt[64][68];   // [d][s]
  __shared__ u16 sP[4][16][72]; // per-wave P strip [q][s]
  const int tid = threadIdx.x;
  const int b = blockIdx.y >> 4, h = blockIdx.y & 15;
  const int w = tid >> 6, lane = tid & 63;
  const int l15 = lane & 15, g = lane >> 4;
  const float c = 0.125f * 1.4426950408889634f;  // scale * log2(e)
  const int ks_r = tid >> 2, ks_c = (tid & 3) * 16;
  const int vs_s = tid & 63, vs_d = (tid >> 6) * 8;
  const u16* kbase = qkv + (size_t)(b * 2048) * 3072 + 1024 + h * 64;
  const u16* vbase = kbase + 1024;

#pragma unroll 1
  for (int pass = 0; pass < 2; ++pass) {
    const int qb = pass == 0 ? (31 - (int)blockIdx.x) : (int)blockIdx.x;

    const size_t qrow = (size_t)(b * 2048 + qb * 64 + w * 16 + l15);
    s16x8 qf0 = *(const s16x8*)(qkv + qrow * 3072 + h * 64 + g * 8);
    s16x8 qf1 = *(const s16x8*)(qkv + qrow * 3072 + h * 64 + 32 + g * 8);

    f32x4 oacc[4] = {};
    float mrow[4] = {-1e30f, -1e30f, -1e30f, -1e30f};
    float lrow[4] = {0.f, 0.f, 0.f, 0.f};  // per-lane partial; reduced in epilogue

    const int nt = qb + 1;
    uint4 kr0, kr1, vr0, vr1;
    {
      const u16* kp = kbase + (size_t)(ks_r)*3072 + ks_c;
      kr0 = *(const uint4*)kp; kr1 = *(const uint4*)(kp + 8);
      const u16* vp = vbase + (size_t)(vs_s)*3072 + vs_d;
      vr0 = *(const uint4*)vp; vr1 = *(const uint4*)(vp + 32);
    }
    for (int t = 0; t < nt; ++t) {
      __syncthreads();
      *(uint4*)(&sK[ks_r][ks_c]) = kr0;
      *(uint4*)(&sK[ks_r][ks_c + 8]) = kr1;
      {
        union { uint4 q4; u16 e[8]; } va, vb;
        va.q4 = vr0; vb.q4 = vr1;
#pragma unroll
        for (int j = 0; j < 8; ++j) sVt[vs_d + j][vs_s] = va.e[j];
#pragma unroll
        for (int j = 0; j < 8; ++j) sVt[vs_d + 32 + j][vs_s] = vb.e[j];
      }
      __syncthreads();
      if (t + 1 < nt) {
        const u16* kp = kbase + (size_t)((t + 1) * 64 + ks_r) * 3072 + ks_c;
        kr0 = *(const uint4*)kp; kr1 = *(const uint4*)(kp + 8);
        const u16* vp = vbase + (size_t)((t + 1) * 64 + vs_s) * 3072 + vs_d;
        vr0 = *(const uint4*)vp; vr1 = *(const uint4*)(vp + 32);
      }

      f32x4 st[4];
#pragma unroll
      for (int n = 0; n < 4; ++n) {
        s16x8 k0 = *(const s16x8*)(&sK[n * 16 + l15][g * 8]);
        s16x8 k1 = *(const s16x8*)(&sK[n * 16 + l15][32 + g * 8]);
        f32x4 a = {};
        a = __builtin_amdgcn_mfma_f32_16x16x32_bf16(qf0, k0, a, 0, 0, 0);
        a = __builtin_amdgcn_mfma_f32_16x16x32_bf16(qf1, k1, a, 0, 0, 0);
        st[n] = a;
      }
      if (t == qb) {
#pragma unroll
        for (int n = 0; n < 4; ++n)
#pragma unroll
          for (int i = 0; i < 4; ++i) {
            const int srel = n * 16 + l15, qrel = w * 16 + 4 * g + i;
            if (srel > qrel) st[n][i] = -1e30f;
          }
      }
      float pm[4];
#pragma unroll
      for (int i = 0; i < 4; ++i)
        pm[i] = fmaxf(fmaxf(st[0][i], st[1][i]), fmaxf(st[2][i], st[3][i]));
#pragma unroll
      for (int msk = 1; msk < 16; msk <<= 1)
#pragma unroll
        for (int i = 0; i < 4; ++i) pm[i] = fmaxf(pm[i], __shfl_xor(pm[i], msk));
      // T13 defer-max: rescale only when some row max rose by > 12 raw units
      // (p then bounded by 2^(12c) ~ 4.5; lrow/oacc stay in the mrow frame)
      bool need = false;
#pragma unroll
      for (int i = 0; i < 4; ++i) need = need || (pm[i] > mrow[i] + 12.f);
      if (__any(need)) {
#pragma unroll
        for (int i = 0; i < 4; ++i) {
          const float mnew = fmaxf(mrow[i], pm[i]);
          const float corr = exp2f((mrow[i] - mnew) * c);
          mrow[i] = mnew;
          lrow[i] *= corr;
#pragma unroll
          for (int dt = 0; dt < 4; ++dt) oacc[dt][i] *= corr;
        }
      }
      float p[4][4];
#pragma unroll
      for (int n = 0; n < 4; ++n)
#pragma unroll
        for (int i = 0; i < 4; ++i) p[n][i] = exp2f((st[n][i] - mrow[i]) * c);
#pragma unroll
      for (int i = 0; i < 4; ++i)
        lrow[i] += (p[0][i] + p[1][i]) + (p[2][i] + p[3][i]);
#pragma unroll
      for (int n = 0; n < 4; ++n)
#pragma unroll
        for (int i = 0; i < 4; ++i)
          sP[w][4 * g + i][n * 16 + l15] = f2bf(p[n][i]);
      s16x8 pf0 = *(const s16x8*)(&sP[w][l15][g * 8]);
      s16x8 pf1 = *(const s16x8*)(&sP[w][l15][32 + g * 8]);
#pragma unroll
      for (int dt = 0; dt < 4; ++dt) {
        s16x8 vf0 = ld_s16x8_a8(&sVt[dt * 16 + l15][g * 8]);
        s16x8 vf1 = ld_s16x8_a8(&sVt[dt * 16 + l15][32 + g * 8]);
        oacc[dt] = __builtin_amdgcn_mfma_f32_16x16x32_bf16(pf0, vf0, oacc[dt], 0, 0, 0);
        oacc[dt] = __builtin_amdgcn_mfma_f32_16x16x32_bf16(pf1, vf1, oacc[dt], 0, 0, 0);
      }
    }

#pragma unroll
    for (int msk = 1; msk < 16; msk <<= 1)
#pragma unroll
      for (int i = 0; i < 4; ++i) lrow[i] += __shfl_xor(lrow[i], msk);
    float inv[4];
#pragma unroll
    for (int i = 0; i < 4; ++i) inv[i] = 1.f / lrow[i];
#pragma unroll
    for (int dt = 0; dt < 4; ++dt)
#pragma unroll
      for (int i = 0; i < 4; ++i) {
        const size_t row = (size_t)(b * 2048 + qb * 64 + w * 16 + 4 * g + i);
        o[row * 1024 + h * 64 + dt * 16 + l15] = f2bf(oacc[dt][i] * inv[i]);
      }
  }
}

// ---------------------------------------------------------------------------
extern "C" void kernel_launch(void* const* d_in, const int* in_sizes, int n_in,
                              void* d_out, int out_size, void* d_ws, size_t ws_size,
                              hipStream_t stream) {
  const float* x     = (const float*)d_in[0];
  const float* Wq    = (const float*)d_in[1];
  const float* Wk    = (const float*)d_in[2];
  const float* Wv    = (const float*)d_in[3];
  const float* Wproj = (const float*)d_in[4];
  const float* bproj = (const float*)d_in[5];
  const float* W1    = (const float*)d_in[6];
  const float* b1    = (const float*)d_in[7];
  const float* W2    = (const float*)d_in[8];
  const float* b2    = (const float*)d_in[9];
  const float* g1    = (const float*)d_in[10];
  const float* be1   = (const float*)d_in[11];
  const float* g2    = (const float*)d_in[12];
  const float* be2   = (const float*)d_in[13];
  float* out = (float*)d_out;

  u16* WqkvT  = (u16*)d_ws;                    // [3072][1024] bf16
  u16* WprojT = WqkvT + (size_t)3072 * 1024;   // [1024][1024]
  u16* W1T    = WprojT + (size_t)1024 * 1024;  // [4096][1024]
  u16* W2T    = W1T + (size_t)4096 * 1024;     // [1024][4096]
  u16* hbuf   = W2T + (size_t)1024 * 4096;     // [4096][1024]
  u16* qkv    = hbuf + (size_t)4096 * 1024;    // [4096][3072]
  u16* obuf   = qkv + (size_t)4096 * 3072;     // [4096][1024]
  float* x2   = (float*)(obuf + (size_t)4096 * 1024);  // [4096][1024] fp32
  u16* a1     = (u16*)(x2 + (size_t)4096 * 1024);      // [4096][4096]

  transpose_f32_bf16<<<dim3(1, 16, 16), 256, 0, stream>>>(Wq, WqkvT,                      64, 65536, 65536, 1024);
  transpose_f32_bf16<<<dim3(1, 16, 16), 256, 0, stream>>>(Wk, WqkvT + (size_t)1024 * 1024, 64, 65536, 65536, 1024);
  transpose_f32_bf16<<<dim3(1, 16, 16), 256, 0, stream>>>(Wv, WqkvT + (size_t)2048 * 1024, 64, 65536, 65536, 1024);
  transpose_f32_bf16<<<dim3(16, 16, 1), 256, 0, stream>>>(Wproj, WprojT, 1024, 0, 0, 1024);
  transpose_f32_bf16<<<dim3(64, 16, 1), 256, 0, stream>>>(W1, W1T, 4096, 0, 0, 1024);
  transpose_f32_bf16<<<dim3(16, 64, 1), 256, 0, stream>>>(W2, W2T, 1024, 0, 0, 4096);

  ln_kernel<<<4096, 256, 0, stream>>>(x, g1, be1, hbuf);
  gemm_kernel<0, 128><<<dim3(24, 32), 256, 0, stream>>>(hbuf, WqkvT, nullptr, nullptr, qkv, 4096, 3072, 1024);
  attn_mfma_kernel<<<dim3(16, 32), 256, 0, stream>>>(qkv, obuf);
  // proj: 128x128 8-phase (grid 8x32 = 256 blocks = 1/CU)
  gemm128_kernel<2><<<dim3(8, 32), 512, 0, stream>>>(obuf, WprojT, bproj, x, x2, 4096, 1024, 1024);
  ln_kernel<<<4096, 256, 0, stream>>>(x2, g2, be2, hbuf);
  // FF1: 256x256 8-phase
  gemm256_kernel<1><<<dim3(16, 16), 512, 0, stream>>>(hbuf, W1T, b1, nullptr, a1, 4096, 4096, 1024);
  // FF2: 128x128 8-phase
  gemm128_kernel<2><<<dim3(8, 32), 512, 0, stream>>>(a1, W2T, b2, x2, out, 4096, 1024, 4096);
}

// Round 14
// 262.588 us; speedup vs baseline: 1.0556x; 1.0556x over previous
//
#include <hip/hip_runtime.h>
#include <stdint.h>

// Round 14: proj & FF2 -> gemm128d: minimum-2-phase schedule (catalog T3) at
// the right geometry — 256 thr / 4 waves (2x2), per-wave 64x64 (0.5 b128
// reads per MFMA vs r13's 0.75), 2 LDS buffers, ONE __syncthreads per K-tile
// placed AFTER the 32 MFMA (drain overlaps compute; m97 drains before).
// Staging/read/epilogue patterns byte-reused from the proven m97 BM=128.
// attn (r13+T13), QKV (m97), FF1 (gemm256 8-phase), LN, transposes frozen.

typedef unsigned short u16;
typedef unsigned int u32;
typedef __attribute__((ext_vector_type(4))) float f32x4;
typedef __attribute__((ext_vector_type(8))) short s16x8;

__device__ __forceinline__ u16 f2bf(float f) {
  u32 u = __builtin_bit_cast(u32, f);
  u += 0x7fffu + ((u >> 16) & 1u);
  return (u16)(u >> 16);
}
// 8-byte-aligned s16x8 load (2 x b64) for odd-stride LDS rows
__device__ __forceinline__ s16x8 ld_s16x8_a8(const u16* p) {
  union { uint2 d[2]; s16x8 v; } u;
  u.d[0] = *(const uint2*)p;
  u.d[1] = *(const uint2*)(p + 4);
  return u.v;
}
// async global->LDS, 16B per lane; lds dest must be wave-uniform base
__device__ __forceinline__ void gload16(const u16* g, u16* lds_base) {
  __builtin_amdgcn_global_load_lds(
      (const __attribute__((address_space(1))) void*)g,
      (__attribute__((address_space(3))) void*)lds_base, 16, 0, 0);
}

// ---------------------------------------------------------------------------
// Tiled transpose fp32 -> bf16: dst[(c)*dstStride + r] = src[r*Ccols + c]
// ---------------------------------------------------------------------------
__global__ __launch_bounds__(256) void transpose_f32_bf16(
    const float* __restrict__ src, u16* __restrict__ dst,
    int Ccols, long srcZ, long dstZ, int dstStride) {
  __shared__ float t[64][65];
  const float* s = src + (size_t)blockIdx.z * srcZ;
  u16* d = dst + (size_t)blockIdx.z * dstZ;
  const int r0 = blockIdx.y * 64, c0 = blockIdx.x * 64;
  const int tr = threadIdx.x >> 4, tc4 = (threadIdx.x & 15) * 4;
#pragma unroll
  for (int p = 0; p < 4; ++p) {
    int r = p * 16 + tr;
    float4 v = *(const float4*)(s + (size_t)(r0 + r) * Ccols + c0 + tc4);
    t[r][tc4 + 0] = v.x; t[r][tc4 + 1] = v.y;
    t[r][tc4 + 2] = v.z; t[r][tc4 + 3] = v.w;
  }
  __syncthreads();
#pragma unroll
  for (int p = 0; p < 4; ++p) {
    int c = p * 16 + tr;
    uint2 pk;
    pk.x = (u32)f2bf(t[tc4 + 0][c]) | ((u32)f2bf(t[tc4 + 1][c]) << 16);
    pk.y = (u32)f2bf(t[tc4 + 2][c]) | ((u32)f2bf(t[tc4 + 3][c]) << 16);
    *(uint2*)(d + (size_t)(c0 + c) * dstStride + r0 + tc4) = pk;
  }
}

// ---------------------------------------------------------------------------
// LayerNorm: one block per row of 1024 fp32; out bf16.
// ---------------------------------------------------------------------------
__global__ __launch_bounds__(256) void ln_kernel(
    const float* __restrict__ x, const float* __restrict__ g,
    const float* __restrict__ be, u16* __restrict__ out) {
  const int row = blockIdx.x, tid = threadIdx.x;
  const float* xr = x + (size_t)row * 1024;
  float4 v = *(const float4*)(xr + tid * 4);
  float s = v.x + v.y + v.z + v.w;
  float q = v.x * v.x + v.y * v.y + v.z * v.z + v.w * v.w;
#pragma unroll
  for (int off = 32; off > 0; off >>= 1) {
    s += __shfl_down(s, off);
    q += __shfl_down(q, off);
  }
  __shared__ float red[8];
  const int wid = tid >> 6, lane = tid & 63;
  if (lane == 0) { red[wid] = s; red[wid + 4] = q; }
  __syncthreads();
  s = red[0] + red[1] + red[2] + red[3];
  q = red[4] + red[5] + red[6] + red[7];
  const float mu = s * (1.f / 1024.f);
  const float var = q * (1.f / 1024.f) - mu * mu;
  const float rs = rsqrtf(var + 1e-5f);
  float4 gv = *(const float4*)(g + tid * 4);
  float4 bv = *(const float4*)(be + tid * 4);
  float o0 = (v.x - mu) * rs * gv.x + bv.x;
  float o1 = (v.y - mu) * rs * gv.y + bv.y;
  float o2 = (v.z - mu) * rs * gv.z + bv.z;
  float o3 = (v.w - mu) * rs * gv.w + bv.w;
  uint2 pk;
  pk.x = (u32)f2bf(o0) | ((u32)f2bf(o1) << 16);
  pk.y = (u32)f2bf(o2) | ((u32)f2bf(o3) << 16);
  *(uint2*)(out + (size_t)row * 1024 + tid * 4) = pk;
}

// ---------------------------------------------------------------------------
// GEMM (m97): C[M,N] = A[M,K] @ BT[N,K]^T (+ bias, relu, residual per EPI)
// ---------------------------------------------------------------------------
template <int EPI, int BM>
__global__ __launch_bounds__(256) void gemm_kernel(
    const u16* __restrict__ A, const u16* __restrict__ BT,
    const float* __restrict__ bias, const float* __restrict__ resid,
    void* __restrict__ out, int M, int N, int K) {
  __shared__ u16 sA[BM][64];
  __shared__ u16 sB[128][64];
  const int tid = threadIdx.x;
  const int m0 = blockIdx.y * BM, n0 = blockIdx.x * 128;
  const int wid = tid >> 6, lane = tid & 63;
  const int wr = (wid >> 1) * (BM / 2), wc = (wid & 1) * 64;
  const int l15 = lane & 15, g = lane >> 4;
  constexpr int MR = BM / 32;
  f32x4 acc[MR][4] = {};
  const int lr = lane >> 3;
  const int cswz = ((lane & 7) * 8) ^ (lr << 3);  // u16 units

  for (int k0 = 0; k0 < K; k0 += 64) {
    __syncthreads();
#pragma unroll
    for (int p = 0; p < MR; ++p) {
      const int row = (p * 4 + wid) * 8 + lr;
      gload16(A + (size_t)(m0 + row) * K + k0 + cswz, &sA[(p * 4 + wid) * 8][0]);
    }
#pragma unroll
    for (int p = 0; p < 4; ++p) {
      const int row = (p * 4 + wid) * 8 + lr;
      gload16(BT + (size_t)(n0 + row) * K + k0 + cswz, &sB[(p * 4 + wid) * 8][0]);
    }
    __syncthreads();
#pragma unroll
    for (int kk = 0; kk < 64; kk += 32) {
      s16x8 af[MR], bf[4];
#pragma unroll
      for (int m = 0; m < MR; ++m) {
        const int R = wr + m * 16 + l15;
        af[m] = *(const s16x8*)(&sA[R][(kk + g * 8) ^ ((R & 7) << 3)]);
      }
#pragma unroll
      for (int n = 0; n < 4; ++n) {
        const int R = wc + n * 16 + l15;
        bf[n] = *(const s16x8*)(&sB[R][(kk + g * 8) ^ ((R & 7) << 3)]);
      }
#pragma unroll
      for (int m = 0; m < MR; ++m)
#pragma unroll
        for (int n = 0; n < 4; ++n)
          acc[m][n] = __builtin_amdgcn_mfma_f32_16x16x32_bf16(af[m], bf[n], acc[m][n], 0, 0, 0);
    }
  }

#pragma unroll
  for (int m = 0; m < MR; ++m) {
#pragma unroll
    for (int n = 0; n < 4; ++n) {
      const int col = n0 + wc + n * 16 + l15;
      float bv = 0.f;
      if (EPI >= 1) bv = bias[col];
#pragma unroll
      for (int i = 0; i < 4; ++i) {
        const int row = m0 + wr + m * 16 + g * 4 + i;
        float v = acc[m][n][i];
        if (EPI >= 1) v += bv;
        if (EPI == 1) v = fmaxf(v, 0.f);
        if (EPI == 2) {
          v += resid[(size_t)row * N + col];
          ((float*)out)[(size_t)row * N + col] = v;
        } else {
          ((u16*)out)[(size_t)row * N + col] = f2bf(v);
        }
      }
    }
  }
}

// ---------------------------------------------------------------------------
// 256x256 8-phase GEMM (T3+T4+T5) — FF1. See round-12 notes.
// ---------------------------------------------------------------------------
template <int EPI>
__global__ __launch_bounds__(512, 2) void gemm256_kernel(
    const u16* __restrict__ A, const u16* __restrict__ BT,
    const float* __restrict__ bias, const float* __restrict__ resid,
    void* __restrict__ out, int M, int N, int K) {
  __shared__ u16 lds[2][2][256][64];  // 128 KiB
  const int tid = threadIdx.x;
  const int wid = tid >> 6, lane = tid & 63;
  const int m0 = blockIdx.y * 256, n0 = blockIdx.x * 256;
  const int wr = (wid >> 2) * 128;
  const int wc = (wid & 3) * 64;
  const int l15 = lane & 15, g = lane >> 4;
  const int lr = lane >> 3;
  const int cswz = ((lane & 7) * 8) ^ (lr << 3);
  const int swz = (l15 & 7) << 3;
  const u16* Abase = A + (size_t)m0 * K;
  const u16* Bbase = BT + (size_t)n0 * K;
  const int nkt = K >> 6;

  f32x4 acc[8][4] = {};
  s16x8 bf[4][2];

  auto issue_half = [&](const u16* Xbase, int xi, int t, int hf) {
    const int b = t & 1;
    const int r0 = hf * 128 + wid * 8;
    gload16(Xbase + (size_t)(r0 + lr) * K + t * 64 + cswz, &lds[b][xi][r0][0]);
    gload16(Xbase + (size_t)(r0 + 64 + lr) * K + t * 64 + cswz, &lds[b][xi][r0 + 64][0]);
  };

  issue_half(Abase, 0, 0, 0);
  issue_half(Abase, 0, 0, 1);
  issue_half(Bbase, 1, 0, 0);
  issue_half(Bbase, 1, 0, 1);
  asm volatile("s_waitcnt vmcnt(0)" ::: "memory");
  __builtin_amdgcn_s_barrier();

  for (int i = 0; i < nkt; i += 2) {
#pragma unroll
    for (int p = 0; p < 4; ++p) {
      s16x8 af[2][2];
#pragma unroll
      for (int q = 0; q < 2; ++q) {
        const int R = wr + (2 * p + q) * 16 + l15;
#pragma unroll
        for (int h = 0; h < 2; ++h)
          af[q][h] = *(const s16x8*)(&lds[0][0][R][(h * 32 + g * 8) ^ swz]);
      }
      if (p == 0) {
#pragma unroll
        for (int n = 0; n < 4; ++n) {
          const int R = wc + n * 16 + l15;
#pragma unroll
          for (int h = 0; h < 2; ++h)
            bf[n][h] = *(const s16x8*)(&lds[0][1][R][(h * 32 + g * 8) ^ swz]);
        }
      }
      if (i + 1 < nkt) {
        if (p == 0) issue_half(Abase, 0, i + 1, 0);
        else if (p == 1) issue_half(Abase, 0, i + 1, 1);
        else if (p == 2) issue_half(Bbase, 1, i + 1, 0);
        else issue_half(Bbase, 1, i + 1, 1);
      }
      __builtin_amdgcn_s_barrier();
      asm volatile("s_waitcnt lgkmcnt(0)" ::: "memory");
      __builtin_amdgcn_sched_barrier(0);
      __builtin_amdgcn_s_setprio(1);
#pragma unroll
      for (int q = 0; q < 2; ++q)
#pragma unroll
        for (int n = 0; n < 4; ++n) {
          acc[2 * p + q][n] = __builtin_amdgcn_mfma_f32_16x16x32_bf16(af[q][0], bf[n][0], acc[2 * p + q][n], 0, 0, 0);
          acc[2 * p + q][n] = __builtin_amdgcn_mfma_f32_16x16x32_bf16(af[q][1], bf[n][1], acc[2 * p + q][n], 0, 0, 0);
        }
      __builtin_amdgcn_s_setprio(0);
      if (p == 3)
        asm volatile("s_waitcnt vmcnt(0)" ::: "memory");
      __builtin_amdgcn_s_barrier();
    }
    if (i + 1 < nkt) {
#pragma unroll
      for (int p = 0; p < 4; ++p) {
        s16x8 af[2][2];
#pragma unroll
        for (int q = 0; q < 2; ++q) {
          const int R = wr + (2 * p + q) * 16 + l15;
#pragma unroll
          for (int h = 0; h < 2; ++h)
            af[q][h] = *(const s16x8*)(&lds[1][0][R][(h * 32 + g * 8) ^ swz]);
        }
        if (p == 0) {
#pragma unroll
          for (int n = 0; n < 4; ++n) {
            const int R = wc + n * 16 + l15;
#pragma unroll
            for (int h = 0; h < 2; ++h)
              bf[n][h] = *(const s16x8*)(&lds[1][1][R][(h * 32 + g * 8) ^ swz]);
          }
        }
        if (i + 2 < nkt) {
          if (p == 0) issue_half(Abase, 0, i + 2, 0);
          else if (p == 1) issue_half(Abase, 0, i + 2, 1);
          else if (p == 2) issue_half(Bbase, 1, i + 2, 0);
          else issue_half(Bbase, 1, i + 2, 1);
        }
        __builtin_amdgcn_s_barrier();
        asm volatile("s_waitcnt lgkmcnt(0)" ::: "memory");
        __builtin_amdgcn_sched_barrier(0);
        __builtin_amdgcn_s_setprio(1);
#pragma unroll
        for (int q = 0; q < 2; ++q)
#pragma unroll
          for (int n = 0; n < 4; ++n) {
            acc[2 * p + q][n] = __builtin_amdgcn_mfma_f32_16x16x32_bf16(af[q][0], bf[n][0], acc[2 * p + q][n], 0, 0, 0);
            acc[2 * p + q][n] = __builtin_amdgcn_mfma_f32_16x16x32_bf16(af[q][1], bf[n][1], acc[2 * p + q][n], 0, 0, 0);
          }
        __builtin_amdgcn_s_setprio(0);
        if (p == 3)
          asm volatile("s_waitcnt vmcnt(0)" ::: "memory");
        __builtin_amdgcn_s_barrier();
      }
    }
  }

#pragma unroll
  for (int mi = 0; mi < 8; ++mi)
#pragma unroll
    for (int n = 0; n < 4; ++n) {
      const int col = n0 + wc + n * 16 + l15;
      float bv = (EPI >= 1) ? bias[col] : 0.f;
#pragma unroll
      for (int ii = 0; ii < 4; ++ii) {
        const int row = m0 + wr + mi * 16 + g * 4 + ii;
        float v = acc[mi][n][ii];
        if (EPI >= 1) v += bv;
        if (EPI == 1) v = fmaxf(v, 0.f);
        ((u16*)out)[(size_t)row * N + col] = f2bf(v);
      }
    }
}

// ---------------------------------------------------------------------------
// gemm128d: 128x128, 256 thr / 4 waves (2x2), per-wave 64x64, BK=64,
// 2 LDS buffers (64 KiB). Minimum-2-phase schedule: per K-tile
// {issue next tile -> ds_read 16 frags -> 32 MFMA -> __syncthreads}.
// The syncthreads' vmcnt(0) drain lands AFTER compute (overlapped), unlike
// m97 which drains before compute. Staging/read/epilogue = m97 BM=128.
// ---------------------------------------------------------------------------
template <int EPI>
__global__ __launch_bounds__(256, 2) void gemm128d_kernel(
    const u16* __restrict__ A, const u16* __restrict__ BT,
    const float* __restrict__ bias, const float* __restrict__ resid,
    void* __restrict__ out, int M, int N, int K) {
  __shared__ u16 lds[2][2][128][64];  // [buf][0=A,1=B] = 64 KiB
  const int tid = threadIdx.x;
  const int wid = tid >> 6, lane = tid & 63;
  const int m0 = blockIdx.y * 128, n0 = blockIdx.x * 128;
  const int wr = (wid >> 1) * 64, wc = (wid & 1) * 64;
  const int l15 = lane & 15, g = lane >> 4;
  const int lr = lane >> 3;
  const int cswz = ((lane & 7) * 8) ^ (lr << 3);
  const int swz = (l15 & 7) << 3;
  const int nkt = K >> 6;
  f32x4 acc[4][4] = {};

  auto stage = [&](int bsel, int t) {
#pragma unroll
    for (int p = 0; p < 4; ++p) {
      const int row = (p * 4 + wid) * 8;  // wave-uniform LDS base
      gload16(A + (size_t)(m0 + row + lr) * K + t * 64 + cswz, &lds[bsel][0][row][0]);
    }
#pragma unroll
    for (int p = 0; p < 4; ++p) {
      const int row = (p * 4 + wid) * 8;
      gload16(BT + (size_t)(n0 + row + lr) * K + t * 64 + cswz, &lds[bsel][1][row][0]);
    }
  };

  stage(0, 0);
  __syncthreads();  // drains vmcnt(0): tile 0 visible

  int cur = 0;
  for (int i = 0; i < nkt; ++i) {
    if (i + 1 < nkt) stage(cur ^ 1, i + 1);  // buf[cur^1] free since last barrier
    s16x8 af[4][2], bf[4][2];
#pragma unroll
    for (int m = 0; m < 4; ++m) {
      const int R = wr + m * 16 + l15;
#pragma unroll
      for (int h = 0; h < 2; ++h)
        af[m][h] = *(const s16x8*)(&lds[cur][0][R][(h * 32 + g * 8) ^ swz]);
    }
#pragma unroll
    for (int n = 0; n < 4; ++n) {
      const int R = wc + n * 16 + l15;
#pragma unroll
      for (int h = 0; h < 2; ++h)
        bf[n][h] = *(const s16x8*)(&lds[cur][1][R][(h * 32 + g * 8) ^ swz]);
    }
    __builtin_amdgcn_s_setprio(1);
#pragma unroll
    for (int m = 0; m < 4; ++m)
#pragma unroll
      for (int n = 0; n < 4; ++n) {
        acc[m][n] = __builtin_amdgcn_mfma_f32_16x16x32_bf16(af[m][0], bf[n][0], acc[m][n], 0, 0, 0);
        acc[m][n] = __builtin_amdgcn_mfma_f32_16x16x32_bf16(af[m][1], bf[n][1], acc[m][n], 0, 0, 0);
      }
    __builtin_amdgcn_s_setprio(0);
    __syncthreads();  // waits vmcnt(0) (next tile staged) + all reads consumed
    cur ^= 1;
  }

#pragma unroll
  for (int m = 0; m < 4; ++m) {
#pragma unroll
    for (int n = 0; n < 4; ++n) {
      const int col = n0 + wc + n * 16 + l15;
      float bv = (EPI >= 1) ? bias[col] : 0.f;
#pragma unroll
      for (int i = 0; i < 4; ++i) {
        const int row = m0 + wr + m * 16 + g * 4 + i;
        float v = acc[m][n][i];
        if (EPI >= 1) v += bv;
        if (EPI == 1) v = fmaxf(v, 0.f);
        if (EPI == 2) {
          v += resid[(size_t)row * N + col];
          ((float*)out)[(size_t)row * N + col] = v;
        } else {
          ((u16*)out)[(size_t)row * N + col] = f2bf(v);
        }
      }
    }
  }
}

// ---------------------------------------------------------------------------
// MFMA causal flash attention (round-8 base + T13 defer-max).
// Paired q-tiles {31-bx, bx}; T14 reg-prefetch staging. grid (16, B*H), 256.
// ---------------------------------------------------------------------------
__global__ __launch_bounds__(256) void attn_mfma_kernel(
    const u16* __restrict__ qkv, u16* __restrict__ o) {
  __shared__ u16 sK[64][72];    // [s][d]
  __shared__ u16 sVt[64][68];   // [d][s]
  __shared__ u16 sP[4][16][72]; // per-wave P strip [q][s]
  const int tid = threadIdx.x;
  const int b = blockIdx.y >> 4, h = blockIdx.y & 15;
  const int w = tid >> 6, lane = tid & 63;
  const int l15 = lane & 15, g = lane >> 4;
  const float c = 0.125f * 1.4426950408889634f;  // scale * log2(e)
  const int ks_r = tid >> 2, ks_c = (tid & 3) * 16;
  const int vs_s = tid & 63, vs_d = (tid >> 6) * 8;
  const u16* kbase = qkv + (size_t)(b * 2048) * 3072 + 1024 + h * 64;
  const u16* vbase = kbase + 1024;

#pragma unroll 1
  for (int pass = 0; pass < 2; ++pass) {
    const int qb = pass == 0 ? (31 - (int)blockIdx.x) : (int)blockIdx.x;

    const size_t qrow = (size_t)(b * 2048 + qb * 64 + w * 16 + l15);
    s16x8 qf0 = *(const s16x8*)(qkv + qrow * 3072 + h * 64 + g * 8);
    s16x8 qf1 = *(const s16x8*)(qkv + qrow * 3072 + h * 64 + 32 + g * 8);

    f32x4 oacc[4] = {};
    float mrow[4] = {-1e30f, -1e30f, -1e30f, -1e30f};
    float lrow[4] = {0.f, 0.f, 0.f, 0.f};  // per-lane partial; reduced in epilogue

    const int nt = qb + 1;
    uint4 kr0, kr1, vr0, vr1;
    {
      const u16* kp = kbase + (size_t)(ks_r)*3072 + ks_c;
      kr0 = *(const uint4*)kp; kr1 = *(const uint4*)(kp + 8);
      const u16* vp = vbase + (size_t)(vs_s)*3072 + vs_d;
      vr0 = *(const uint4*)vp; vr1 = *(const uint4*)(vp + 32);
    }
    for (int t = 0; t < nt; ++t) {
      __syncthreads();
      *(uint4*)(&sK[ks_r][ks_c]) = kr0;
      *(uint4*)(&sK[ks_r][ks_c + 8]) = kr1;
      {
        union { uint4 q4; u16 e[8]; } va, vb;
        va.q4 = vr0; vb.q4 = vr1;
#pragma unroll
        for (int j = 0; j < 8; ++j) sVt[vs_d + j][vs_s] = va.e[j];
#pragma unroll
        for (int j = 0; j < 8; ++j) sVt[vs_d + 32 + j][vs_s] = vb.e[j];
      }
      __syncthreads();
      if (t + 1 < nt) {
        const u16* kp = kbase + (size_t)((t + 1) * 64 + ks_r) * 3072 + ks_c;
        kr0 = *(const uint4*)kp; kr1 = *(const uint4*)(kp + 8);
        const u16* vp = vbase + (size_t)((t + 1) * 64 + vs_s) * 3072 + vs_d;
        vr0 = *(const uint4*)vp; vr1 = *(const uint4*)(vp + 32);
      }

      f32x4 st[4];
#pragma unroll
      for (int n = 0; n < 4; ++n) {
        s16x8 k0 = *(const s16x8*)(&sK[n * 16 + l15][g * 8]);
        s16x8 k1 = *(const s16x8*)(&sK[n * 16 + l15][32 + g * 8]);
        f32x4 a = {};
        a = __builtin_amdgcn_mfma_f32_16x16x32_bf16(qf0, k0, a, 0, 0, 0);
        a = __builtin_amdgcn_mfma_f32_16x16x32_bf16(qf1, k1, a, 0, 0, 0);
        st[n] = a;
      }
      if (t == qb) {
#pragma unroll
        for (int n = 0; n < 4; ++n)
#pragma unroll
          for (int i = 0; i < 4; ++i) {
            const int srel = n * 16 + l15, qrel = w * 16 + 4 * g + i;
            if (srel > qrel) st[n][i] = -1e30f;
          }
      }
      float pm[4];
#pragma unroll
      for (int i = 0; i < 4; ++i)
        pm[i] = fmaxf(fmaxf(st[0][i], st[1][i]), fmaxf(st[2][i], st[3][i]));
#pragma unroll
      for (int msk = 1; msk < 16; msk <<= 1)
#pragma unroll
        for (int i = 0; i < 4; ++i) pm[i] = fmaxf(pm[i], __shfl_xor(pm[i], msk));
      // T13 defer-max: rescale only when some row max rose by > 12 raw units
      bool need = false;
#pragma unroll
      for (int i = 0; i < 4; ++i) need = need || (pm[i] > mrow[i] + 12.f);
      if (__any(need)) {
#pragma unroll
        for (int i = 0; i < 4; ++i) {
          const float mnew = fmaxf(mrow[i], pm[i]);
          const float corr = exp2f((mrow[i] - mnew) * c);
          mrow[i] = mnew;
          lrow[i] *= corr;
#pragma unroll
          for (int dt = 0; dt < 4; ++dt) oacc[dt][i] *= corr;
        }
      }
      float p[4][4];
#pragma unroll
      for (int n = 0; n < 4; ++n)
#pragma unroll
        for (int i = 0; i < 4; ++i) p[n][i] = exp2f((st[n][i] - mrow[i]) * c);
#pragma unroll
      for (int i = 0; i < 4; ++i)
        lrow[i] += (p[0][i] + p[1][i]) + (p[2][i] + p[3][i]);
#pragma unroll
      for (int n = 0; n < 4; ++n)
#pragma unroll
        for (int i = 0; i < 4; ++i)
          sP[w][4 * g + i][n * 16 + l15] = f2bf(p[n][i]);
      s16x8 pf0 = *(const s16x8*)(&sP[w][l15][g * 8]);
      s16x8 pf1 = *(const s16x8*)(&sP[w][l15][32 + g * 8]);
#pragma unroll
      for (int dt = 0; dt < 4; ++dt) {
        s16x8 vf0 = ld_s16x8_a8(&sVt[dt * 16 + l15][g * 8]);
        s16x8 vf1 = ld_s16x8_a8(&sVt[dt * 16 + l15][32 + g * 8]);
        oacc[dt] = __builtin_amdgcn_mfma_f32_16x16x32_bf16(pf0, vf0, oacc[dt], 0, 0, 0);
        oacc[dt] = __builtin_amdgcn_mfma_f32_16x16x32_bf16(pf1, vf1, oacc[dt], 0, 0, 0);
      }
    }

#pragma unroll
    for (int msk = 1; msk < 16; msk <<= 1)
#pragma unroll
      for (int i = 0; i < 4; ++i) lrow[i] += __shfl_xor(lrow[i], msk);
    float inv[4];
#pragma unroll
    for (int i = 0; i < 4; ++i) inv[i] = 1.f / lrow[i];
#pragma unroll
    for (int dt = 0; dt < 4; ++dt)
#pragma unroll
      for (int i = 0; i < 4; ++i) {
        const size_t row = (size_t)(b * 2048 + qb * 64 + w * 16 + 4 * g + i);
        o[row * 1024 + h * 64 + dt * 16 + l15] = f2bf(oacc[dt][i] * inv[i]);
      }
  }
}

// ---------------------------------------------------------------------------
extern "C" void kernel_launch(void* const* d_in, const int* in_sizes, int n_in,
                              void* d_out, int out_size, void* d_ws, size_t ws_size,
                              hipStream_t stream) {
  const float* x     = (const float*)d_in[0];
  const float* Wq    = (const float*)d_in[1];
  const float* Wk    = (const float*)d_in[2];
  const float* Wv    = (const float*)d_in[3];
  const float* Wproj = (const float*)d_in[4];
  const float* bproj = (const float*)d_in[5];
  const float* W1    = (const float*)d_in[6];
  const float* b1    = (const float*)d_in[7];
  const float* W2    = (const float*)d_in[8];
  const float* b2    = (const float*)d_in[9];
  const float* g1    = (const float*)d_in[10];
  const float* be1   = (const float*)d_in[11];
  const float* g2    = (const float*)d_in[12];
  const float* be2   = (const float*)d_in[13];
  float* out = (float*)d_out;

  u16* WqkvT  = (u16*)d_ws;                    // [3072][1024] bf16
  u16* WprojT = WqkvT + (size_t)3072 * 1024;   // [1024][1024]
  u16* W1T    = WprojT + (size_t)1024 * 1024;  // [4096][1024]
  u16* W2T    = W1T + (size_t)4096 * 1024;     // [1024][4096]
  u16* hbuf   = W2T + (size_t)1024 * 4096;     // [4096][1024]
  u16* qkv    = hbuf + (size_t)4096 * 1024;    // [4096][3072]
  u16* obuf   = qkv + (size_t)4096 * 3072;     // [4096][1024]
  float* x2   = (float*)(obuf + (size_t)4096 * 1024);  // [4096][1024] fp32
  u16* a1     = (u16*)(x2 + (size_t)4096 * 1024);      // [4096][4096]

  transpose_f32_bf16<<<dim3(1, 16, 16), 256, 0, stream>>>(Wq, WqkvT,                      64, 65536, 65536, 1024);
  transpose_f32_bf16<<<dim3(1, 16, 16), 256, 0, stream>>>(Wk, WqkvT + (size_t)1024 * 1024, 64, 65536, 65536, 1024);
  transpose_f32_bf16<<<dim3(1, 16, 16), 256, 0, stream>>>(Wv, WqkvT + (size_t)2048 * 1024, 64, 65536, 65536, 1024);
  transpose_f32_bf16<<<dim3(16, 16, 1), 256, 0, stream>>>(Wproj, WprojT, 1024, 0, 0, 1024);
  transpose_f32_bf16<<<dim3(64, 16, 1), 256, 0, stream>>>(W1, W1T, 4096, 0, 0, 1024);
  transpose_f32_bf16<<<dim3(16, 64, 1), 256, 0, stream>>>(W2, W2T, 1024, 0, 0, 4096);

  ln_kernel<<<4096, 256, 0, stream>>>(x, g1, be1, hbuf);
  gemm_kernel<0, 128><<<dim3(24, 32), 256, 0, stream>>>(hbuf, WqkvT, nullptr, nullptr, qkv, 4096, 3072, 1024);
  attn_mfma_kernel<<<dim3(16, 32), 256, 0, stream>>>(qkv, obuf);
  // proj: 128x128 2-phase dbuf (grid 8x32 = 256 blocks)
  gemm128d_kernel<2><<<dim3(8, 32), 256, 0, stream>>>(obuf, WprojT, bproj, x, x2, 4096, 1024, 1024);
  ln_kernel<<<4096, 256, 0, stream>>>(x2, g2, be2, hbuf);
  // FF1: 256x256 8-phase
  gemm256_kernel<1><<<dim3(16, 16), 512, 0, stream>>>(hbuf, W1T, b1, nullptr, a1, 4096, 4096, 1024);
  // FF2: 128x128 2-phase dbuf
  gemm128d_kernel<2><<<dim3(8, 32), 256, 0, stream>>>(a1, W2T, b2, x2, out, 4096, 1024, 4096);
}

// Round 15
// 245.770 us; speedup vs baseline: 1.1278x; 1.0684x over previous
//
#include <hip/hip_runtime.h>
#include <stdint.h>

// Round 15: (a) FF2 split-K x2 in ONE launch (grid 8x32x2 = 512 blocks co-
// resident at 2/CU vs 256@1/CU before) writing fp32 partials into the dead
// hbuf+qkv region; combine kernel adds P0+P1+bias+resid -> out. (b) all 6
// weight transposes fused into one 3072-block launch. attn/QKV/proj/FF1/LN
// frozen from round 14.

typedef unsigned short u16;
typedef unsigned int u32;
typedef __attribute__((ext_vector_type(4))) float f32x4;
typedef __attribute__((ext_vector_type(8))) short s16x8;

__device__ __forceinline__ u16 f2bf(float f) {
  u32 u = __builtin_bit_cast(u32, f);
  u += 0x7fffu + ((u >> 16) & 1u);
  return (u16)(u >> 16);
}
__device__ __forceinline__ s16x8 ld_s16x8_a8(const u16* p) {
  union { uint2 d[2]; s16x8 v; } u;
  u.d[0] = *(const uint2*)p;
  u.d[1] = *(const uint2*)(p + 4);
  return u.v;
}
__device__ __forceinline__ void gload16(const u16* g, u16* lds_base) {
  __builtin_amdgcn_global_load_lds(
      (const __attribute__((address_space(1))) void*)g,
      (__attribute__((address_space(3))) void*)lds_base, 16, 0, 0);
}

// ---------------------------------------------------------------------------
// Fused weight transposes fp32 -> bf16^T, one launch, 3072 blocks:
// [0,768): Wq/Wk/Wv (256 each) -> WqkvT; [768,1024): Wproj; [1024,2048): W1;
// [2048,3072): W2. Body identical to the old per-kernel version.
// ---------------------------------------------------------------------------
__global__ __launch_bounds__(256) void transpose_all_kernel(
    const float* __restrict__ Wq, const float* __restrict__ Wk,
    const float* __restrict__ Wv, const float* __restrict__ Wproj,
    const float* __restrict__ W1, const float* __restrict__ W2,
    u16* __restrict__ WqkvT, u16* __restrict__ WprojT,
    u16* __restrict__ W1T, u16* __restrict__ W2T) {
  const int bid = blockIdx.x;
  const float* src; u16* dst; int Ccols, dstStride, r0, c0;
  if (bid < 768) {             // Wq/Wk/Wv: [H=16][1024][64] -> [3072][1024]
    const int sub = bid >> 8, rem = bid & 255;
    const int z = rem >> 4, y = rem & 15;
    src = (sub == 0 ? Wq : sub == 1 ? Wk : Wv) + (size_t)z * 65536;
    dst = WqkvT + (size_t)sub * 1024 * 1024 + (size_t)z * 65536;
    Ccols = 64; dstStride = 1024; r0 = y * 64; c0 = 0;
  } else if (bid < 1024) {     // Wproj: [1024][1024]
    const int rem = bid - 768, xx = rem & 15, y = rem >> 4;
    src = Wproj; dst = WprojT; Ccols = 1024; dstStride = 1024;
    r0 = y * 64; c0 = xx * 64;
  } else if (bid < 2048) {     // W1: [1024][4096] -> [4096][1024]
    const int rem = bid - 1024, xx = rem & 63, y = rem >> 6;
    src = W1; dst = W1T; Ccols = 4096; dstStride = 1024;
    r0 = y * 64; c0 = xx * 64;
  } else {                     // W2: [4096][1024] -> [1024][4096]
    const int rem = bid - 2048, xx = rem & 15, y = rem >> 4;
    src = W2; dst = W2T; Ccols = 1024; dstStride = 4096;
    r0 = y * 64; c0 = xx * 64;
  }
  __shared__ float t[64][65];
  const int tr = threadIdx.x >> 4, tc4 = (threadIdx.x & 15) * 4;
#pragma unroll
  for (int p = 0; p < 4; ++p) {
    int r = p * 16 + tr;
    float4 v = *(const float4*)(src + (size_t)(r0 + r) * Ccols + c0 + tc4);
    t[r][tc4 + 0] = v.x; t[r][tc4 + 1] = v.y;
    t[r][tc4 + 2] = v.z; t[r][tc4 + 3] = v.w;
  }
  __syncthreads();
#pragma unroll
  for (int p = 0; p < 4; ++p) {
    int c = p * 16 + tr;
    uint2 pk;
    pk.x = (u32)f2bf(t[tc4 + 0][c]) | ((u32)f2bf(t[tc4 + 1][c]) << 16);
    pk.y = (u32)f2bf(t[tc4 + 2][c]) | ((u32)f2bf(t[tc4 + 3][c]) << 16);
    *(uint2*)(dst + (size_t)(c0 + c) * dstStride + r0 + tc4) = pk;
  }
}

// ---------------------------------------------------------------------------
// LayerNorm: one block per row of 1024 fp32; out bf16.
// ---------------------------------------------------------------------------
__global__ __launch_bounds__(256) void ln_kernel(
    const float* __restrict__ x, const float* __restrict__ g,
    const float* __restrict__ be, u16* __restrict__ out) {
  const int row = blockIdx.x, tid = threadIdx.x;
  const float* xr = x + (size_t)row * 1024;
  float4 v = *(const float4*)(xr + tid * 4);
  float s = v.x + v.y + v.z + v.w;
  float q = v.x * v.x + v.y * v.y + v.z * v.z + v.w * v.w;
#pragma unroll
  for (int off = 32; off > 0; off >>= 1) {
    s += __shfl_down(s, off);
    q += __shfl_down(q, off);
  }
  __shared__ float red[8];
  const int wid = tid >> 6, lane = tid & 63;
  if (lane == 0) { red[wid] = s; red[wid + 4] = q; }
  __syncthreads();
  s = red[0] + red[1] + red[2] + red[3];
  q = red[4] + red[5] + red[6] + red[7];
  const float mu = s * (1.f / 1024.f);
  const float var = q * (1.f / 1024.f) - mu * mu;
  const float rs = rsqrtf(var + 1e-5f);
  float4 gv = *(const float4*)(g + tid * 4);
  float4 bv = *(const float4*)(be + tid * 4);
  float o0 = (v.x - mu) * rs * gv.x + bv.x;
  float o1 = (v.y - mu) * rs * gv.y + bv.y;
  float o2 = (v.z - mu) * rs * gv.z + bv.z;
  float o3 = (v.w - mu) * rs * gv.w + bv.w;
  uint2 pk;
  pk.x = (u32)f2bf(o0) | ((u32)f2bf(o1) << 16);
  pk.y = (u32)f2bf(o2) | ((u32)f2bf(o3) << 16);
  *(uint2*)(out + (size_t)row * 1024 + tid * 4) = pk;
}

// ---------------------------------------------------------------------------
// combine: out = P0 + P1 + bias + resid  (fp32, one row per block)
// ---------------------------------------------------------------------------
__global__ __launch_bounds__(256) void combine_kernel(
    const float* __restrict__ P, const float* __restrict__ resid,
    const float* __restrict__ bias, float* __restrict__ out) {
  const int row = blockIdx.x, c4 = threadIdx.x * 4;
  const size_t idx = (size_t)row * 1024 + c4;
  float4 p0 = *(const float4*)(P + idx);
  float4 p1 = *(const float4*)(P + 4194304 + idx);
  float4 r  = *(const float4*)(resid + idx);
  float4 bb = *(const float4*)(bias + c4);
  float4 o;
  o.x = p0.x + p1.x + r.x + bb.x;
  o.y = p0.y + p1.y + r.y + bb.y;
  o.z = p0.z + p1.z + r.z + bb.z;
  o.w = p0.w + p1.w + r.w + bb.w;
  *(float4*)(out + idx) = o;
}

// ---------------------------------------------------------------------------
// GEMM (m97): C[M,N] = A[M,K] @ BT[N,K]^T (+ epilogues) — QKV only now.
// ---------------------------------------------------------------------------
template <int EPI, int BM>
__global__ __launch_bounds__(256) void gemm_kernel(
    const u16* __restrict__ A, const u16* __restrict__ BT,
    const float* __restrict__ bias, const float* __restrict__ resid,
    void* __restrict__ out, int M, int N, int K) {
  __shared__ u16 sA[BM][64];
  __shared__ u16 sB[128][64];
  const int tid = threadIdx.x;
  const int m0 = blockIdx.y * BM, n0 = blockIdx.x * 128;
  const int wid = tid >> 6, lane = tid & 63;
  const int wr = (wid >> 1) * (BM / 2), wc = (wid & 1) * 64;
  const int l15 = lane & 15, g = lane >> 4;
  constexpr int MR = BM / 32;
  f32x4 acc[MR][4] = {};
  const int lr = lane >> 3;
  const int cswz = ((lane & 7) * 8) ^ (lr << 3);

  for (int k0 = 0; k0 < K; k0 += 64) {
    __syncthreads();
#pragma unroll
    for (int p = 0; p < MR; ++p) {
      const int row = (p * 4 + wid) * 8 + lr;
      gload16(A + (size_t)(m0 + row) * K + k0 + cswz, &sA[(p * 4 + wid) * 8][0]);
    }
#pragma unroll
    for (int p = 0; p < 4; ++p) {
      const int row = (p * 4 + wid) * 8 + lr;
      gload16(BT + (size_t)(n0 + row) * K + k0 + cswz, &sB[(p * 4 + wid) * 8][0]);
    }
    __syncthreads();
#pragma unroll
    for (int kk = 0; kk < 64; kk += 32) {
      s16x8 af[MR], bf[4];
#pragma unroll
      for (int m = 0; m < MR; ++m) {
        const int R = wr + m * 16 + l15;
        af[m] = *(const s16x8*)(&sA[R][(kk + g * 8) ^ ((R & 7) << 3)]);
      }
#pragma unroll
      for (int n = 0; n < 4; ++n) {
        const int R = wc + n * 16 + l15;
        bf[n] = *(const s16x8*)(&sB[R][(kk + g * 8) ^ ((R & 7) << 3)]);
      }
#pragma unroll
      for (int m = 0; m < MR; ++m)
#pragma unroll
        for (int n = 0; n < 4; ++n)
          acc[m][n] = __builtin_amdgcn_mfma_f32_16x16x32_bf16(af[m], bf[n], acc[m][n], 0, 0, 0);
    }
  }

#pragma unroll
  for (int m = 0; m < MR; ++m) {
#pragma unroll
    for (int n = 0; n < 4; ++n) {
      const int col = n0 + wc + n * 16 + l15;
      float bv = 0.f;
      if (EPI >= 1) bv = bias[col];
#pragma unroll
      for (int i = 0; i < 4; ++i) {
        const int row = m0 + wr + m * 16 + g * 4 + i;
        float v = acc[m][n][i];
        if (EPI >= 1) v += bv;
        if (EPI == 1) v = fmaxf(v, 0.f);
        if (EPI == 2) {
          v += resid[(size_t)row * N + col];
          ((float*)out)[(size_t)row * N + col] = v;
        } else {
          ((u16*)out)[(size_t)row * N + col] = f2bf(v);
        }
      }
    }
  }
}

// ---------------------------------------------------------------------------
// 256x256 8-phase GEMM (T3+T4+T5) — FF1.
// ---------------------------------------------------------------------------
template <int EPI>
__global__ __launch_bounds__(512, 2) void gemm256_kernel(
    const u16* __restrict__ A, const u16* __restrict__ BT,
    const float* __restrict__ bias, const float* __restrict__ resid,
    void* __restrict__ out, int M, int N, int K) {
  __shared__ u16 lds[2][2][256][64];  // 128 KiB
  const int tid = threadIdx.x;
  const int wid = tid >> 6, lane = tid & 63;
  const int m0 = blockIdx.y * 256, n0 = blockIdx.x * 256;
  const int wr = (wid >> 2) * 128;
  const int wc = (wid & 3) * 64;
  const int l15 = lane & 15, g = lane >> 4;
  const int lr = lane >> 3;
  const int cswz = ((lane & 7) * 8) ^ (lr << 3);
  const int swz = (l15 & 7) << 3;
  const u16* Abase = A + (size_t)m0 * K;
  const u16* Bbase = BT + (size_t)n0 * K;
  const int nkt = K >> 6;

  f32x4 acc[8][4] = {};
  s16x8 bf[4][2];

  auto issue_half = [&](const u16* Xbase, int xi, int t, int hf) {
    const int b = t & 1;
    const int r0 = hf * 128 + wid * 8;
    gload16(Xbase + (size_t)(r0 + lr) * K + t * 64 + cswz, &lds[b][xi][r0][0]);
    gload16(Xbase + (size_t)(r0 + 64 + lr) * K + t * 64 + cswz, &lds[b][xi][r0 + 64][0]);
  };

  issue_half(Abase, 0, 0, 0);
  issue_half(Abase, 0, 0, 1);
  issue_half(Bbase, 1, 0, 0);
  issue_half(Bbase, 1, 0, 1);
  asm volatile("s_waitcnt vmcnt(0)" ::: "memory");
  __builtin_amdgcn_s_barrier();

  for (int i = 0; i < nkt; i += 2) {
#pragma unroll
    for (int p = 0; p < 4; ++p) {
      s16x8 af[2][2];
#pragma unroll
      for (int q = 0; q < 2; ++q) {
        const int R = wr + (2 * p + q) * 16 + l15;
#pragma unroll
        for (int h = 0; h < 2; ++h)
          af[q][h] = *(const s16x8*)(&lds[0][0][R][(h * 32 + g * 8) ^ swz]);
      }
      if (p == 0) {
#pragma unroll
        for (int n = 0; n < 4; ++n) {
          const int R = wc + n * 16 + l15;
#pragma unroll
          for (int h = 0; h < 2; ++h)
            bf[n][h] = *(const s16x8*)(&lds[0][1][R][(h * 32 + g * 8) ^ swz]);
        }
      }
      if (i + 1 < nkt) {
        if (p == 0) issue_half(Abase, 0, i + 1, 0);
        else if (p == 1) issue_half(Abase, 0, i + 1, 1);
        else if (p == 2) issue_half(Bbase, 1, i + 1, 0);
        else issue_half(Bbase, 1, i + 1, 1);
      }
      __builtin_amdgcn_s_barrier();
      asm volatile("s_waitcnt lgkmcnt(0)" ::: "memory");
      __builtin_amdgcn_sched_barrier(0);
      __builtin_amdgcn_s_setprio(1);
#pragma unroll
      for (int q = 0; q < 2; ++q)
#pragma unroll
        for (int n = 0; n < 4; ++n) {
          acc[2 * p + q][n] = __builtin_amdgcn_mfma_f32_16x16x32_bf16(af[q][0], bf[n][0], acc[2 * p + q][n], 0, 0, 0);
          acc[2 * p + q][n] = __builtin_amdgcn_mfma_f32_16x16x32_bf16(af[q][1], bf[n][1], acc[2 * p + q][n], 0, 0, 0);
        }
      __builtin_amdgcn_s_setprio(0);
      if (p == 3)
        asm volatile("s_waitcnt vmcnt(0)" ::: "memory");
      __builtin_amdgcn_s_barrier();
    }
    if (i + 1 < nkt) {
#pragma unroll
      for (int p = 0; p < 4; ++p) {
        s16x8 af[2][2];
#pragma unroll
        for (int q = 0; q < 2; ++q) {
          const int R = wr + (2 * p + q) * 16 + l15;
#pragma unroll
          for (int h = 0; h < 2; ++h)
            af[q][h] = *(const s16x8*)(&lds[1][0][R][(h * 32 + g * 8) ^ swz]);
        }
        if (p == 0) {
#pragma unroll
          for (int n = 0; n < 4; ++n) {
            const int R = wc + n * 16 + l15;
#pragma unroll
            for (int h = 0; h < 2; ++h)
              bf[n][h] = *(const s16x8*)(&lds[1][1][R][(h * 32 + g * 8) ^ swz]);
          }
        }
        if (i + 2 < nkt) {
          if (p == 0) issue_half(Abase, 0, i + 2, 0);
          else if (p == 1) issue_half(Abase, 0, i + 2, 1);
          else if (p == 2) issue_half(Bbase, 1, i + 2, 0);
          else issue_half(Bbase, 1, i + 2, 1);
        }
        __builtin_amdgcn_s_barrier();
        asm volatile("s_waitcnt lgkmcnt(0)" ::: "memory");
        __builtin_amdgcn_sched_barrier(0);
        __builtin_amdgcn_s_setprio(1);
#pragma unroll
        for (int q = 0; q < 2; ++q)
#pragma unroll
          for (int n = 0; n < 4; ++n) {
            acc[2 * p + q][n] = __builtin_amdgcn_mfma_f32_16x16x32_bf16(af[q][0], bf[n][0], acc[2 * p + q][n], 0, 0, 0);
            acc[2 * p + q][n] = __builtin_amdgcn_mfma_f32_16x16x32_bf16(af[q][1], bf[n][1], acc[2 * p + q][n], 0, 0, 0);
          }
        __builtin_amdgcn_s_setprio(0);
        if (p == 3)
          asm volatile("s_waitcnt vmcnt(0)" ::: "memory");
        __builtin_amdgcn_s_barrier();
      }
    }
  }

#pragma unroll
  for (int mi = 0; mi < 8; ++mi)
#pragma unroll
    for (int n = 0; n < 4; ++n) {
      const int col = n0 + wc + n * 16 + l15;
      float bv = (EPI >= 1) ? bias[col] : 0.f;
#pragma unroll
      for (int ii = 0; ii < 4; ++ii) {
        const int row = m0 + wr + mi * 16 + g * 4 + ii;
        float v = acc[mi][n][ii];
        if (EPI >= 1) v += bv;
        if (EPI == 1) v = fmaxf(v, 0.f);
        ((u16*)out)[(size_t)row * N + col] = f2bf(v);
      }
    }
}

// ---------------------------------------------------------------------------
// gemm128d: 128x128 2-phase dbuf (see r14). lda = row stride of A/BT.
// EPI 2: +bias+resid -> fp32. EPI 3: split-K partial — blockIdx.z selects the
// K-chunk (A/BT advanced by z*K elements) and the fp32 output slab (z*M*N).
// ---------------------------------------------------------------------------
template <int EPI>
__global__ __launch_bounds__(256, 2) void gemm128d_kernel(
    const u16* __restrict__ A, const u16* __restrict__ BT,
    const float* __restrict__ bias, const float* __restrict__ resid,
    void* __restrict__ out, int M, int N, int K, int lda) {
  __shared__ u16 lds[2][2][128][64];  // 64 KiB
  const int tid = threadIdx.x;
  const int wid = tid >> 6, lane = tid & 63;
  const int m0 = blockIdx.y * 128, n0 = blockIdx.x * 128;
  const int wr = (wid >> 1) * 64, wc = (wid & 1) * 64;
  const int l15 = lane & 15, g = lane >> 4;
  const int lr = lane >> 3;
  const int cswz = ((lane & 7) * 8) ^ (lr << 3);
  const int swz = (l15 & 7) << 3;
  const int nkt = K >> 6;
  f32x4 acc[4][4] = {};

  if (EPI == 3) {  // split-K: advance into this z-chunk
    const int koff = (int)blockIdx.z * K;
    A += koff; BT += koff;
  }

  auto stage = [&](int bsel, int t) {
#pragma unroll
    for (int p = 0; p < 4; ++p) {
      const int row = (p * 4 + wid) * 8;
      gload16(A + (size_t)(m0 + row + lr) * lda + t * 64 + cswz, &lds[bsel][0][row][0]);
    }
#pragma unroll
    for (int p = 0; p < 4; ++p) {
      const int row = (p * 4 + wid) * 8;
      gload16(BT + (size_t)(n0 + row + lr) * lda + t * 64 + cswz, &lds[bsel][1][row][0]);
    }
  };

  stage(0, 0);
  __syncthreads();

  int cur = 0;
  for (int i = 0; i < nkt; ++i) {
    if (i + 1 < nkt) stage(cur ^ 1, i + 1);
    s16x8 af[4][2], bf[4][2];
#pragma unroll
    for (int m = 0; m < 4; ++m) {
      const int R = wr + m * 16 + l15;
#pragma unroll
      for (int h = 0; h < 2; ++h)
        af[m][h] = *(const s16x8*)(&lds[cur][0][R][(h * 32 + g * 8) ^ swz]);
    }
#pragma unroll
    for (int n = 0; n < 4; ++n) {
      const int R = wc + n * 16 + l15;
#pragma unroll
      for (int h = 0; h < 2; ++h)
        bf[n][h] = *(const s16x8*)(&lds[cur][1][R][(h * 32 + g * 8) ^ swz]);
    }
    __builtin_amdgcn_s_setprio(1);
#pragma unroll
    for (int m = 0; m < 4; ++m)
#pragma unroll
      for (int n = 0; n < 4; ++n) {
        acc[m][n] = __builtin_amdgcn_mfma_f32_16x16x32_bf16(af[m][0], bf[n][0], acc[m][n], 0, 0, 0);
        acc[m][n] = __builtin_amdgcn_mfma_f32_16x16x32_bf16(af[m][1], bf[n][1], acc[m][n], 0, 0, 0);
      }
    __builtin_amdgcn_s_setprio(0);
    __syncthreads();
    cur ^= 1;
  }

  float* outf = (float*)out;
  if (EPI == 3) outf += (size_t)blockIdx.z * M * N;
#pragma unroll
  for (int m = 0; m < 4; ++m) {
#pragma unroll
    for (int n = 0; n < 4; ++n) {
      const int col = n0 + wc + n * 16 + l15;
      float bv = (EPI == 1 || EPI == 2) ? bias[col] : 0.f;
#pragma unroll
      for (int i = 0; i < 4; ++i) {
        const int row = m0 + wr + m * 16 + g * 4 + i;
        float v = acc[m][n][i];
        if (EPI == 1 || EPI == 2) v += bv;
        if (EPI == 1) v = fmaxf(v, 0.f);
        if (EPI == 2) {
          v += resid[(size_t)row * N + col];
          outf[(size_t)row * N + col] = v;
        } else if (EPI == 3) {
          outf[(size_t)row * N + col] = v;
        } else {
          ((u16*)out)[(size_t)row * N + col] = f2bf(v);
        }
      }
    }
  }
}

// ---------------------------------------------------------------------------
// MFMA causal flash attention (round-8 base + T13 defer-max). Frozen.
// ---------------------------------------------------------------------------
__global__ __launch_bounds__(256) void attn_mfma_kernel(
    const u16* __restrict__ qkv, u16* __restrict__ o) {
  __shared__ u16 sK[64][72];
  __shared__ u16 sVt[64][68];
  __shared__ u16 sP[4][16][72];
  const int tid = threadIdx.x;
  const int b = blockIdx.y >> 4, h = blockIdx.y & 15;
  const int w = tid >> 6, lane = tid & 63;
  const int l15 = lane & 15, g = lane >> 4;
  const float c = 0.125f * 1.4426950408889634f;
  const int ks_r = tid >> 2, ks_c = (tid & 3) * 16;
  const int vs_s = tid & 63, vs_d = (tid >> 6) * 8;
  const u16* kbase = qkv + (size_t)(b * 2048) * 3072 + 1024 + h * 64;
  const u16* vbase = kbase + 1024;

#pragma unroll 1
  for (int pass = 0; pass < 2; ++pass) {
    const int qb = pass == 0 ? (31 - (int)blockIdx.x) : (int)blockIdx.x;

    const size_t qrow = (size_t)(b * 2048 + qb * 64 + w * 16 + l15);
    s16x8 qf0 = *(const s16x8*)(qkv + qrow * 3072 + h * 64 + g * 8);
    s16x8 qf1 = *(const s16x8*)(qkv + qrow * 3072 + h * 64 + 32 + g * 8);

    f32x4 oacc[4] = {};
    float mrow[4] = {-1e30f, -1e30f, -1e30f, -1e30f};
    float lrow[4] = {0.f, 0.f, 0.f, 0.f};

    const int nt = qb + 1;
    uint4 kr0, kr1, vr0, vr1;
    {
      const u16* kp = kbase + (size_t)(ks_r)*3072 + ks_c;
      kr0 = *(const uint4*)kp; kr1 = *(const uint4*)(kp + 8);
      const u16* vp = vbase + (size_t)(vs_s)*3072 + vs_d;
      vr0 = *(const uint4*)vp; vr1 = *(const uint4*)(vp + 32);
    }
    for (int t = 0; t < nt; ++t) {
      __syncthreads();
      *(uint4*)(&sK[ks_r][ks_c]) = kr0;
      *(uint4*)(&sK[ks_r][ks_c + 8]) = kr1;
      {
        union { uint4 q4; u16 e[8]; } va, vb;
        va.q4 = vr0; vb.q4 = vr1;
#pragma unroll
        for (int j = 0; j < 8; ++j) sVt[vs_d + j][vs_s] = va.e[j];
#pragma unroll
        for (int j = 0; j < 8; ++j) sVt[vs_d + 32 + j][vs_s] = vb.e[j];
      }
      __syncthreads();
      if (t + 1 < nt) {
        const u16* kp = kbase + (size_t)((t + 1) * 64 + ks_r) * 3072 + ks_c;
        kr0 = *(const uint4*)kp; kr1 = *(const uint4*)(kp + 8);
        const u16* vp = vbase + (size_t)((t + 1) * 64 + vs_s) * 3072 + vs_d;
        vr0 = *(const uint4*)vp; vr1 = *(const uint4*)(vp + 32);
      }

      f32x4 st[4];
#pragma unroll
      for (int n = 0; n < 4; ++n) {
        s16x8 k0 = *(const s16x8*)(&sK[n * 16 + l15][g * 8]);
        s16x8 k1 = *(const s16x8*)(&sK[n * 16 + l15][32 + g * 8]);
        f32x4 a = {};
        a = __builtin_amdgcn_mfma_f32_16x16x32_bf16(qf0, k0, a, 0, 0, 0);
        a = __builtin_amdgcn_mfma_f32_16x16x32_bf16(qf1, k1, a, 0, 0, 0);
        st[n] = a;
      }
      if (t == qb) {
#pragma unroll
        for (int n = 0; n < 4; ++n)
#pragma unroll
          for (int i = 0; i < 4; ++i) {
            const int srel = n * 16 + l15, qrel = w * 16 + 4 * g + i;
            if (srel > qrel) st[n][i] = -1e30f;
          }
      }
      float pm[4];
#pragma unroll
      for (int i = 0; i < 4; ++i)
        pm[i] = fmaxf(fmaxf(st[0][i], st[1][i]), fmaxf(st[2][i], st[3][i]));
#pragma unroll
      for (int msk = 1; msk < 16; msk <<= 1)
#pragma unroll
        for (int i = 0; i < 4; ++i) pm[i] = fmaxf(pm[i], __shfl_xor(pm[i], msk));
      bool need = false;
#pragma unroll
      for (int i = 0; i < 4; ++i) need = need || (pm[i] > mrow[i] + 12.f);
      if (__any(need)) {
#pragma unroll
        for (int i = 0; i < 4; ++i) {
          const float mnew = fmaxf(mrow[i], pm[i]);
          const float corr = exp2f((mrow[i] - mnew) * c);
          mrow[i] = mnew;
          lrow[i] *= corr;
#pragma unroll
          for (int dt = 0; dt < 4; ++dt) oacc[dt][i] *= corr;
        }
      }
      float p[4][4];
#pragma unroll
      for (int n = 0; n < 4; ++n)
#pragma unroll
        for (int i = 0; i < 4; ++i) p[n][i] = exp2f((st[n][i] - mrow[i]) * c);
#pragma unroll
      for (int i = 0; i < 4; ++i)
        lrow[i] += (p[0][i] + p[1][i]) + (p[2][i] + p[3][i]);
#pragma unroll
      for (int n = 0; n < 4; ++n)
#pragma unroll
        for (int i = 0; i < 4; ++i)
          sP[w][4 * g + i][n * 16 + l15] = f2bf(p[n][i]);
      s16x8 pf0 = *(const s16x8*)(&sP[w][l15][g * 8]);
      s16x8 pf1 = *(const s16x8*)(&sP[w][l15][32 + g * 8]);
#pragma unroll
      for (int dt = 0; dt < 4; ++dt) {
        s16x8 vf0 = ld_s16x8_a8(&sVt[dt * 16 + l15][g * 8]);
        s16x8 vf1 = ld_s16x8_a8(&sVt[dt * 16 + l15][32 + g * 8]);
        oacc[dt] = __builtin_amdgcn_mfma_f32_16x16x32_bf16(pf0, vf0, oacc[dt], 0, 0, 0);
        oacc[dt] = __builtin_amdgcn_mfma_f32_16x16x32_bf16(pf1, vf1, oacc[dt], 0, 0, 0);
      }
    }

#pragma unroll
    for (int msk = 1; msk < 16; msk <<= 1)
#pragma unroll
      for (int i = 0; i < 4; ++i) lrow[i] += __shfl_xor(lrow[i], msk);
    float inv[4];
#pragma unroll
    for (int i = 0; i < 4; ++i) inv[i] = 1.f / lrow[i];
#pragma unroll
    for (int dt = 0; dt < 4; ++dt)
#pragma unroll
      for (int i = 0; i < 4; ++i) {
        const size_t row = (size_t)(b * 2048 + qb * 64 + w * 16 + 4 * g + i);
        o[row * 1024 + h * 64 + dt * 16 + l15] = f2bf(oacc[dt][i] * inv[i]);
      }
  }
}

// ---------------------------------------------------------------------------
extern "C" void kernel_launch(void* const* d_in, const int* in_sizes, int n_in,
                              void* d_out, int out_size, void* d_ws, size_t ws_size,
                              hipStream_t stream) {
  const float* x     = (const float*)d_in[0];
  const float* Wq    = (const float*)d_in[1];
  const float* Wk    = (const float*)d_in[2];
  const float* Wv    = (const float*)d_in[3];
  const float* Wproj = (const float*)d_in[4];
  const float* bproj = (const float*)d_in[5];
  const float* W1    = (const float*)d_in[6];
  const float* b1    = (const float*)d_in[7];
  const float* W2    = (const float*)d_in[8];
  const float* b2    = (const float*)d_in[9];
  const float* g1    = (const float*)d_in[10];
  const float* be1   = (const float*)d_in[11];
  const float* g2    = (const float*)d_in[12];
  const float* be2   = (const float*)d_in[13];
  float* out = (float*)d_out;

  u16* WqkvT  = (u16*)d_ws;                    // [3072][1024] bf16
  u16* WprojT = WqkvT + (size_t)3072 * 1024;   // [1024][1024]
  u16* W1T    = WprojT + (size_t)1024 * 1024;  // [4096][1024]
  u16* W2T    = W1T + (size_t)4096 * 1024;     // [1024][4096]
  u16* hbuf   = W2T + (size_t)1024 * 4096;     // [4096][1024]
  u16* qkv    = hbuf + (size_t)4096 * 1024;    // [4096][3072]
  u16* obuf   = qkv + (size_t)4096 * 3072;     // [4096][1024]
  float* x2   = (float*)(obuf + (size_t)4096 * 1024);  // [4096][1024] fp32
  u16* a1     = (u16*)(x2 + (size_t)4096 * 1024);      // [4096][4096]
  // FF2 split-K partials: 2 x [4096][1024] fp32 = 32 MB over the hbuf+qkv
  // region (hbuf dead after FF1 consumes it; qkv dead after attn).
  float* Pk   = (float*)hbuf;

  transpose_all_kernel<<<3072, 256, 0, stream>>>(Wq, Wk, Wv, Wproj, W1, W2,
                                                 WqkvT, WprojT, W1T, W2T);
  ln_kernel<<<4096, 256, 0, stream>>>(x, g1, be1, hbuf);
  gemm_kernel<0, 128><<<dim3(24, 32), 256, 0, stream>>>(hbuf, WqkvT, nullptr, nullptr, qkv, 4096, 3072, 1024);
  attn_mfma_kernel<<<dim3(16, 32), 256, 0, stream>>>(qkv, obuf);
  // proj: 128x128 2-phase dbuf
  gemm128d_kernel<2><<<dim3(8, 32), 256, 0, stream>>>(obuf, WprojT, bproj, x, x2, 4096, 1024, 1024, 1024);
  ln_kernel<<<4096, 256, 0, stream>>>(x2, g2, be2, hbuf);
  // FF1: 256x256 8-phase (reads hbuf; must precede the split-K partials
  // which overwrite the hbuf region)
  gemm256_kernel<1><<<dim3(16, 16), 512, 0, stream>>>(hbuf, W1T, b1, nullptr, a1, 4096, 4096, 1024);
  // FF2 split-K x2: 512 blocks co-resident (2/CU), partials into Pk
  gemm128d_kernel<3><<<dim3(8, 32, 2), 256, 0, stream>>>(a1, W2T, nullptr, nullptr, Pk, 4096, 1024, 2048, 4096);
  combine_kernel<<<4096, 256, 0, stream>>>(Pk, x2, b2, out);
}

// Round 16
// 241.206 us; speedup vs baseline: 1.1491x; 1.0189x over previous
//
#include <hip/hip_runtime.h>
#include <stdint.h>

// Round 16: (a) attn -> 8-wave QBLK=128: 512 thr, per-wave work IDENTICAL to
// r8 (16 q-rows, 1 m-tile, VGPR ~72) but K/V staging shared by 128 q-rows
// (2x amortization); paired {15-bx, bx} -> 256 blocks, uniform 34 tiles/CU.
// (b) QKV -> gemm256 8-phase (grid 12x16). Everything else frozen from r15.

typedef unsigned short u16;
typedef unsigned int u32;
typedef __attribute__((ext_vector_type(4))) float f32x4;
typedef __attribute__((ext_vector_type(8))) short s16x8;

__device__ __forceinline__ u16 f2bf(float f) {
  u32 u = __builtin_bit_cast(u32, f);
  u += 0x7fffu + ((u >> 16) & 1u);
  return (u16)(u >> 16);
}
__device__ __forceinline__ s16x8 ld_s16x8_a8(const u16* p) {
  union { uint2 d[2]; s16x8 v; } u;
  u.d[0] = *(const uint2*)p;
  u.d[1] = *(const uint2*)(p + 4);
  return u.v;
}
__device__ __forceinline__ void gload16(const u16* g, u16* lds_base) {
  __builtin_amdgcn_global_load_lds(
      (const __attribute__((address_space(1))) void*)g,
      (__attribute__((address_space(3))) void*)lds_base, 16, 0, 0);
}

// ---------------------------------------------------------------------------
// Fused weight transposes fp32 -> bf16^T, one launch, 3072 blocks.
// ---------------------------------------------------------------------------
__global__ __launch_bounds__(256) void transpose_all_kernel(
    const float* __restrict__ Wq, const float* __restrict__ Wk,
    const float* __restrict__ Wv, const float* __restrict__ Wproj,
    const float* __restrict__ W1, const float* __restrict__ W2,
    u16* __restrict__ WqkvT, u16* __restrict__ WprojT,
    u16* __restrict__ W1T, u16* __restrict__ W2T) {
  const int bid = blockIdx.x;
  const float* src; u16* dst; int Ccols, dstStride, r0, c0;
  if (bid < 768) {
    const int sub = bid >> 8, rem = bid & 255;
    const int z = rem >> 4, y = rem & 15;
    src = (sub == 0 ? Wq : sub == 1 ? Wk : Wv) + (size_t)z * 65536;
    dst = WqkvT + (size_t)sub * 1024 * 1024 + (size_t)z * 65536;
    Ccols = 64; dstStride = 1024; r0 = y * 64; c0 = 0;
  } else if (bid < 1024) {
    const int rem = bid - 768, xx = rem & 15, y = rem >> 4;
    src = Wproj; dst = WprojT; Ccols = 1024; dstStride = 1024;
    r0 = y * 64; c0 = xx * 64;
  } else if (bid < 2048) {
    const int rem = bid - 1024, xx = rem & 63, y = rem >> 6;
    src = W1; dst = W1T; Ccols = 4096; dstStride = 1024;
    r0 = y * 64; c0 = xx * 64;
  } else {
    const int rem = bid - 2048, xx = rem & 15, y = rem >> 4;
    src = W2; dst = W2T; Ccols = 1024; dstStride = 4096;
    r0 = y * 64; c0 = xx * 64;
  }
  __shared__ float t[64][65];
  const int tr = threadIdx.x >> 4, tc4 = (threadIdx.x & 15) * 4;
#pragma unroll
  for (int p = 0; p < 4; ++p) {
    int r = p * 16 + tr;
    float4 v = *(const float4*)(src + (size_t)(r0 + r) * Ccols + c0 + tc4);
    t[r][tc4 + 0] = v.x; t[r][tc4 + 1] = v.y;
    t[r][tc4 + 2] = v.z; t[r][tc4 + 3] = v.w;
  }
  __syncthreads();
#pragma unroll
  for (int p = 0; p < 4; ++p) {
    int c = p * 16 + tr;
    uint2 pk;
    pk.x = (u32)f2bf(t[tc4 + 0][c]) | ((u32)f2bf(t[tc4 + 1][c]) << 16);
    pk.y = (u32)f2bf(t[tc4 + 2][c]) | ((u32)f2bf(t[tc4 + 3][c]) << 16);
    *(uint2*)(dst + (size_t)(c0 + c) * dstStride + r0 + tc4) = pk;
  }
}

// ---------------------------------------------------------------------------
// LayerNorm: one block per row of 1024 fp32; out bf16.
// ---------------------------------------------------------------------------
__global__ __launch_bounds__(256) void ln_kernel(
    const float* __restrict__ x, const float* __restrict__ g,
    const float* __restrict__ be, u16* __restrict__ out) {
  const int row = blockIdx.x, tid = threadIdx.x;
  const float* xr = x + (size_t)row * 1024;
  float4 v = *(const float4*)(xr + tid * 4);
  float s = v.x + v.y + v.z + v.w;
  float q = v.x * v.x + v.y * v.y + v.z * v.z + v.w * v.w;
#pragma unroll
  for (int off = 32; off > 0; off >>= 1) {
    s += __shfl_down(s, off);
    q += __shfl_down(q, off);
  }
  __shared__ float red[8];
  const int wid = tid >> 6, lane = tid & 63;
  if (lane == 0) { red[wid] = s; red[wid + 4] = q; }
  __syncthreads();
  s = red[0] + red[1] + red[2] + red[3];
  q = red[4] + red[5] + red[6] + red[7];
  const float mu = s * (1.f / 1024.f);
  const float var = q * (1.f / 1024.f) - mu * mu;
  const float rs = rsqrtf(var + 1e-5f);
  float4 gv = *(const float4*)(g + tid * 4);
  float4 bv = *(const float4*)(be + tid * 4);
  float o0 = (v.x - mu) * rs * gv.x + bv.x;
  float o1 = (v.y - mu) * rs * gv.y + bv.y;
  float o2 = (v.z - mu) * rs * gv.z + bv.z;
  float o3 = (v.w - mu) * rs * gv.w + bv.w;
  uint2 pk;
  pk.x = (u32)f2bf(o0) | ((u32)f2bf(o1) << 16);
  pk.y = (u32)f2bf(o2) | ((u32)f2bf(o3) << 16);
  *(uint2*)(out + (size_t)row * 1024 + tid * 4) = pk;
}

// ---------------------------------------------------------------------------
// combine: out = P0 + P1 + bias + resid  (fp32)
// ---------------------------------------------------------------------------
__global__ __launch_bounds__(256) void combine_kernel(
    const float* __restrict__ P, const float* __restrict__ resid,
    const float* __restrict__ bias, float* __restrict__ out) {
  const int row = blockIdx.x, c4 = threadIdx.x * 4;
  const size_t idx = (size_t)row * 1024 + c4;
  float4 p0 = *(const float4*)(P + idx);
  float4 p1 = *(const float4*)(P + 4194304 + idx);
  float4 r  = *(const float4*)(resid + idx);
  float4 bb = *(const float4*)(bias + c4);
  float4 o;
  o.x = p0.x + p1.x + r.x + bb.x;
  o.y = p0.y + p1.y + r.y + bb.y;
  o.z = p0.z + p1.z + r.z + bb.z;
  o.w = p0.w + p1.w + r.w + bb.w;
  *(float4*)(out + idx) = o;
}

// ---------------------------------------------------------------------------
// 256x256 8-phase GEMM (T3+T4+T5) — QKV + FF1.
// ---------------------------------------------------------------------------
template <int EPI>
__global__ __launch_bounds__(512, 2) void gemm256_kernel(
    const u16* __restrict__ A, const u16* __restrict__ BT,
    const float* __restrict__ bias, const float* __restrict__ resid,
    void* __restrict__ out, int M, int N, int K) {
  __shared__ u16 lds[2][2][256][64];  // 128 KiB
  const int tid = threadIdx.x;
  const int wid = tid >> 6, lane = tid & 63;
  const int m0 = blockIdx.y * 256, n0 = blockIdx.x * 256;
  const int wr = (wid >> 2) * 128;
  const int wc = (wid & 3) * 64;
  const int l15 = lane & 15, g = lane >> 4;
  const int lr = lane >> 3;
  const int cswz = ((lane & 7) * 8) ^ (lr << 3);
  const int swz = (l15 & 7) << 3;
  const u16* Abase = A + (size_t)m0 * K;
  const u16* Bbase = BT + (size_t)n0 * K;
  const int nkt = K >> 6;

  f32x4 acc[8][4] = {};
  s16x8 bf[4][2];

  auto issue_half = [&](const u16* Xbase, int xi, int t, int hf) {
    const int b = t & 1;
    const int r0 = hf * 128 + wid * 8;
    gload16(Xbase + (size_t)(r0 + lr) * K + t * 64 + cswz, &lds[b][xi][r0][0]);
    gload16(Xbase + (size_t)(r0 + 64 + lr) * K + t * 64 + cswz, &lds[b][xi][r0 + 64][0]);
  };

  issue_half(Abase, 0, 0, 0);
  issue_half(Abase, 0, 0, 1);
  issue_half(Bbase, 1, 0, 0);
  issue_half(Bbase, 1, 0, 1);
  asm volatile("s_waitcnt vmcnt(0)" ::: "memory");
  __builtin_amdgcn_s_barrier();

  for (int i = 0; i < nkt; i += 2) {
#pragma unroll
    for (int p = 0; p < 4; ++p) {
      s16x8 af[2][2];
#pragma unroll
      for (int q = 0; q < 2; ++q) {
        const int R = wr + (2 * p + q) * 16 + l15;
#pragma unroll
        for (int h = 0; h < 2; ++h)
          af[q][h] = *(const s16x8*)(&lds[0][0][R][(h * 32 + g * 8) ^ swz]);
      }
      if (p == 0) {
#pragma unroll
        for (int n = 0; n < 4; ++n) {
          const int R = wc + n * 16 + l15;
#pragma unroll
          for (int h = 0; h < 2; ++h)
            bf[n][h] = *(const s16x8*)(&lds[0][1][R][(h * 32 + g * 8) ^ swz]);
        }
      }
      if (i + 1 < nkt) {
        if (p == 0) issue_half(Abase, 0, i + 1, 0);
        else if (p == 1) issue_half(Abase, 0, i + 1, 1);
        else if (p == 2) issue_half(Bbase, 1, i + 1, 0);
        else issue_half(Bbase, 1, i + 1, 1);
      }
      __builtin_amdgcn_s_barrier();
      asm volatile("s_waitcnt lgkmcnt(0)" ::: "memory");
      __builtin_amdgcn_sched_barrier(0);
      __builtin_amdgcn_s_setprio(1);
#pragma unroll
      for (int q = 0; q < 2; ++q)
#pragma unroll
        for (int n = 0; n < 4; ++n) {
          acc[2 * p + q][n] = __builtin_amdgcn_mfma_f32_16x16x32_bf16(af[q][0], bf[n][0], acc[2 * p + q][n], 0, 0, 0);
          acc[2 * p + q][n] = __builtin_amdgcn_mfma_f32_16x16x32_bf16(af[q][1], bf[n][1], acc[2 * p + q][n], 0, 0, 0);
        }
      __builtin_amdgcn_s_setprio(0);
      if (p == 3)
        asm volatile("s_waitcnt vmcnt(0)" ::: "memory");
      __builtin_amdgcn_s_barrier();
    }
    if (i + 1 < nkt) {
#pragma unroll
      for (int p = 0; p < 4; ++p) {
        s16x8 af[2][2];
#pragma unroll
        for (int q = 0; q < 2; ++q) {
          const int R = wr + (2 * p + q) * 16 + l15;
#pragma unroll
          for (int h = 0; h < 2; ++h)
            af[q][h] = *(const s16x8*)(&lds[1][0][R][(h * 32 + g * 8) ^ swz]);
        }
        if (p == 0) {
#pragma unroll
          for (int n = 0; n < 4; ++n) {
            const int R = wc + n * 16 + l15;
#pragma unroll
            for (int h = 0; h < 2; ++h)
              bf[n][h] = *(const s16x8*)(&lds[1][1][R][(h * 32 + g * 8) ^ swz]);
          }
        }
        if (i + 2 < nkt) {
          if (p == 0) issue_half(Abase, 0, i + 2, 0);
          else if (p == 1) issue_half(Abase, 0, i + 2, 1);
          else if (p == 2) issue_half(Bbase, 1, i + 2, 0);
          else issue_half(Bbase, 1, i + 2, 1);
        }
        __builtin_amdgcn_s_barrier();
        asm volatile("s_waitcnt lgkmcnt(0)" ::: "memory");
        __builtin_amdgcn_sched_barrier(0);
        __builtin_amdgcn_s_setprio(1);
#pragma unroll
        for (int q = 0; q < 2; ++q)
#pragma unroll
          for (int n = 0; n < 4; ++n) {
            acc[2 * p + q][n] = __builtin_amdgcn_mfma_f32_16x16x32_bf16(af[q][0], bf[n][0], acc[2 * p + q][n], 0, 0, 0);
            acc[2 * p + q][n] = __builtin_amdgcn_mfma_f32_16x16x32_bf16(af[q][1], bf[n][1], acc[2 * p + q][n], 0, 0, 0);
          }
        __builtin_amdgcn_s_setprio(0);
        if (p == 3)
          asm volatile("s_waitcnt vmcnt(0)" ::: "memory");
        __builtin_amdgcn_s_barrier();
      }
    }
  }

#pragma unroll
  for (int mi = 0; mi < 8; ++mi)
#pragma unroll
    for (int n = 0; n < 4; ++n) {
      const int col = n0 + wc + n * 16 + l15;
      float bv = (EPI >= 1) ? bias[col] : 0.f;
#pragma unroll
      for (int ii = 0; ii < 4; ++ii) {
        const int row = m0 + wr + mi * 16 + g * 4 + ii;
        float v = acc[mi][n][ii];
        if (EPI >= 1) v += bv;
        if (EPI == 1) v = fmaxf(v, 0.f);
        ((u16*)out)[(size_t)row * N + col] = f2bf(v);
      }
    }
}

// ---------------------------------------------------------------------------
// gemm128d: 128x128 2-phase dbuf. EPI 2: +bias+resid -> fp32.
// EPI 3: split-K partial (blockIdx.z selects K-chunk + output slab).
// ---------------------------------------------------------------------------
template <int EPI>
__global__ __launch_bounds__(256, 2) void gemm128d_kernel(
    const u16* __restrict__ A, const u16* __restrict__ BT,
    const float* __restrict__ bias, const float* __restrict__ resid,
    void* __restrict__ out, int M, int N, int K, int lda) {
  __shared__ u16 lds[2][2][128][64];  // 64 KiB
  const int tid = threadIdx.x;
  const int wid = tid >> 6, lane = tid & 63;
  const int m0 = blockIdx.y * 128, n0 = blockIdx.x * 128;
  const int wr = (wid >> 1) * 64, wc = (wid & 1) * 64;
  const int l15 = lane & 15, g = lane >> 4;
  const int lr = lane >> 3;
  const int cswz = ((lane & 7) * 8) ^ (lr << 3);
  const int swz = (l15 & 7) << 3;
  const int nkt = K >> 6;
  f32x4 acc[4][4] = {};

  if (EPI == 3) {
    const int koff = (int)blockIdx.z * K;
    A += koff; BT += koff;
  }

  auto stage = [&](int bsel, int t) {
#pragma unroll
    for (int p = 0; p < 4; ++p) {
      const int row = (p * 4 + wid) * 8;
      gload16(A + (size_t)(m0 + row + lr) * lda + t * 64 + cswz, &lds[bsel][0][row][0]);
    }
#pragma unroll
    for (int p = 0; p < 4; ++p) {
      const int row = (p * 4 + wid) * 8;
      gload16(BT + (size_t)(n0 + row + lr) * lda + t * 64 + cswz, &lds[bsel][1][row][0]);
    }
  };

  stage(0, 0);
  __syncthreads();

  int cur = 0;
  for (int i = 0; i < nkt; ++i) {
    if (i + 1 < nkt) stage(cur ^ 1, i + 1);
    s16x8 af[4][2], bf[4][2];
#pragma unroll
    for (int m = 0; m < 4; ++m) {
      const int R = wr + m * 16 + l15;
#pragma unroll
      for (int h = 0; h < 2; ++h)
        af[m][h] = *(const s16x8*)(&lds[cur][0][R][(h * 32 + g * 8) ^ swz]);
    }
#pragma unroll
    for (int n = 0; n < 4; ++n) {
      const int R = wc + n * 16 + l15;
#pragma unroll
      for (int h = 0; h < 2; ++h)
        bf[n][h] = *(const s16x8*)(&lds[cur][1][R][(h * 32 + g * 8) ^ swz]);
    }
    __builtin_amdgcn_s_setprio(1);
#pragma unroll
    for (int m = 0; m < 4; ++m)
#pragma unroll
      for (int n = 0; n < 4; ++n) {
        acc[m][n] = __builtin_amdgcn_mfma_f32_16x16x32_bf16(af[m][0], bf[n][0], acc[m][n], 0, 0, 0);
        acc[m][n] = __builtin_amdgcn_mfma_f32_16x16x32_bf16(af[m][1], bf[n][1], acc[m][n], 0, 0, 0);
      }
    __builtin_amdgcn_s_setprio(0);
    __syncthreads();
    cur ^= 1;
  }

  float* outf = (float*)out;
  if (EPI == 3) outf += (size_t)blockIdx.z * M * N;
#pragma unroll
  for (int m = 0; m < 4; ++m) {
#pragma unroll
    for (int n = 0; n < 4; ++n) {
      const int col = n0 + wc + n * 16 + l15;
      float bv = (EPI == 1 || EPI == 2) ? bias[col] : 0.f;
#pragma unroll
      for (int i = 0; i < 4; ++i) {
        const int row = m0 + wr + m * 16 + g * 4 + i;
        float v = acc[m][n][i];
        if (EPI == 1 || EPI == 2) v += bv;
        if (EPI == 1) v = fmaxf(v, 0.f);
        if (EPI == 2) {
          v += resid[(size_t)row * N + col];
          outf[(size_t)row * N + col] = v;
        } else if (EPI == 3) {
          outf[(size_t)row * N + col] = v;
        } else {
          ((u16*)out)[(size_t)row * N + col] = f2bf(v);
        }
      }
    }
  }
}

// ---------------------------------------------------------------------------
// MFMA causal flash attention, 8-wave QBLK=128. Per-wave work identical to
// the r8 kernel (16 q-rows, 1 m-tile); K/V staged once per 128 q-rows.
// Paired q-super-tiles {15-bx, bx} -> grid (8, B*H) = 256 blocks, uniform
// 34 KV-tiles per block. T14 reg-prefetch; T13 defer-max.
// ---------------------------------------------------------------------------
__global__ __launch_bounds__(512) void attn_mfma_kernel(
    const u16* __restrict__ qkv, u16* __restrict__ o) {
  __shared__ u16 sK[64][72];     // [s][d]
  __shared__ u16 sVt[64][68];    // [d][s]
  __shared__ u16 sP[8][16][72];  // per-wave P strip
  const int tid = threadIdx.x;
  const int b = blockIdx.y >> 4, h = blockIdx.y & 15;
  const int w = tid >> 6, lane = tid & 63;
  const int l15 = lane & 15, g = lane >> 4;
  const float c = 0.125f * 1.4426950408889634f;  // scale * log2(e)
  // staging (512 threads): K = 64x64 u16 = 8 KB = 512 x 16B
  const int ks_r = tid >> 3, ks_c = (tid & 7) * 8;
  // V^T: 512 threads x 8 scalars
  const int vs_s = tid & 63, vs_d = (tid >> 6) * 8;
  const u16* kbase = qkv + (size_t)(b * 2048) * 3072 + 1024 + h * 64;
  const u16* vbase = kbase + 1024;

#pragma unroll 1
  for (int pass = 0; pass < 2; ++pass) {
    const int qb = pass == 0 ? (15 - (int)blockIdx.x) : (int)blockIdx.x;
    const int qw = qb * 128 + w * 16;  // wave q base

    const size_t qrow = (size_t)(b * 2048 + qw + l15);
    s16x8 qf0 = *(const s16x8*)(qkv + qrow * 3072 + h * 64 + g * 8);
    s16x8 qf1 = *(const s16x8*)(qkv + qrow * 3072 + h * 64 + 32 + g * 8);

    f32x4 oacc[4] = {};
    float mrow[4] = {-1e30f, -1e30f, -1e30f, -1e30f};
    float lrow[4] = {0.f, 0.f, 0.f, 0.f};  // per-lane partial; reduced at end

    const int nt = 2 * qb + 2;
    uint4 kr0, vr0;
    {
      const u16* kp = kbase + (size_t)(ks_r)*3072 + ks_c;
      kr0 = *(const uint4*)kp;
      const u16* vp = vbase + (size_t)(vs_s)*3072 + vs_d;
      vr0 = *(const uint4*)vp;
    }
    for (int t = 0; t < nt; ++t) {
      __syncthreads();
      *(uint4*)(&sK[ks_r][ks_c]) = kr0;
      {
        union { uint4 q4; u16 e[8]; } va;
        va.q4 = vr0;
#pragma unroll
        for (int j = 0; j < 8; ++j) sVt[vs_d + j][vs_s] = va.e[j];
      }
      __syncthreads();
      if (t + 1 < nt) {  // T14: issue next tile's loads under compute
        const u16* kp = kbase + (size_t)((t + 1) * 64 + ks_r) * 3072 + ks_c;
        kr0 = *(const uint4*)kp;
        const u16* vp = vbase + (size_t)((t + 1) * 64 + vs_s) * 3072 + vs_d;
        vr0 = *(const uint4*)vp;
      }

      f32x4 st[4];
#pragma unroll
      for (int n = 0; n < 4; ++n) {
        s16x8 k0 = *(const s16x8*)(&sK[n * 16 + l15][g * 8]);
        s16x8 k1 = *(const s16x8*)(&sK[n * 16 + l15][32 + g * 8]);
        f32x4 a = {};
        a = __builtin_amdgcn_mfma_f32_16x16x32_bf16(qf0, k0, a, 0, 0, 0);
        a = __builtin_amdgcn_mfma_f32_16x16x32_bf16(qf1, k1, a, 0, 0, 0);
        st[n] = a;
      }
      if (t >= 2 * qb) {  // diagonal spans the last two tiles (absolute idx)
#pragma unroll
        for (int n = 0; n < 4; ++n)
#pragma unroll
          for (int i = 0; i < 4; ++i) {
            const int s_abs = t * 64 + n * 16 + l15;
            const int q_abs = qw + 4 * g + i;
            if (s_abs > q_abs) st[n][i] = -1e30f;
          }
      }
      float pm[4];
#pragma unroll
      for (int i = 0; i < 4; ++i)
        pm[i] = fmaxf(fmaxf(st[0][i], st[1][i]), fmaxf(st[2][i], st[3][i]));
#pragma unroll
      for (int msk = 1; msk < 16; msk <<= 1)
#pragma unroll
        for (int i = 0; i < 4; ++i) pm[i] = fmaxf(pm[i], __shfl_xor(pm[i], msk));
      bool need = false;  // T13 defer-max
#pragma unroll
      for (int i = 0; i < 4; ++i) need = need || (pm[i] > mrow[i] + 12.f);
      if (__any(need)) {
#pragma unroll
        for (int i = 0; i < 4; ++i) {
          const float mnew = fmaxf(mrow[i], pm[i]);
          const float corr = exp2f((mrow[i] - mnew) * c);
          mrow[i] = mnew;
          lrow[i] *= corr;
#pragma unroll
          for (int dt = 0; dt < 4; ++dt) oacc[dt][i] *= corr;
        }
      }
      float p[4][4];
#pragma unroll
      for (int n = 0; n < 4; ++n)
#pragma unroll
        for (int i = 0; i < 4; ++i) p[n][i] = exp2f((st[n][i] - mrow[i]) * c);
#pragma unroll
      for (int i = 0; i < 4; ++i)
        lrow[i] += (p[0][i] + p[1][i]) + (p[2][i] + p[3][i]);
#pragma unroll
      for (int n = 0; n < 4; ++n)
#pragma unroll
        for (int i = 0; i < 4; ++i)
          sP[w][4 * g + i][n * 16 + l15] = f2bf(p[n][i]);
      s16x8 pf0 = *(const s16x8*)(&sP[w][l15][g * 8]);
      s16x8 pf1 = *(const s16x8*)(&sP[w][l15][32 + g * 8]);
#pragma unroll
      for (int dt = 0; dt < 4; ++dt) {
        s16x8 vf0 = ld_s16x8_a8(&sVt[dt * 16 + l15][g * 8]);
        s16x8 vf1 = ld_s16x8_a8(&sVt[dt * 16 + l15][32 + g * 8]);
        oacc[dt] = __builtin_amdgcn_mfma_f32_16x16x32_bf16(pf0, vf0, oacc[dt], 0, 0, 0);
        oacc[dt] = __builtin_amdgcn_mfma_f32_16x16x32_bf16(pf1, vf1, oacc[dt], 0, 0, 0);
      }
    }

#pragma unroll
    for (int msk = 1; msk < 16; msk <<= 1)
#pragma unroll
      for (int i = 0; i < 4; ++i) lrow[i] += __shfl_xor(lrow[i], msk);
    float inv[4];
#pragma unroll
    for (int i = 0; i < 4; ++i) inv[i] = 1.f / lrow[i];
#pragma unroll
    for (int dt = 0; dt < 4; ++dt)
#pragma unroll
      for (int i = 0; i < 4; ++i) {
        const size_t row = (size_t)(b * 2048 + qw + 4 * g + i);
        o[row * 1024 + h * 64 + dt * 16 + l15] = f2bf(oacc[dt][i] * inv[i]);
      }
  }
}

// ---------------------------------------------------------------------------
extern "C" void kernel_launch(void* const* d_in, const int* in_sizes, int n_in,
                              void* d_out, int out_size, void* d_ws, size_t ws_size,
                              hipStream_t stream) {
  const float* x     = (const float*)d_in[0];
  const float* Wq    = (const float*)d_in[1];
  const float* Wk    = (const float*)d_in[2];
  const float* Wv    = (const float*)d_in[3];
  const float* Wproj = (const float*)d_in[4];
  const float* bproj = (const float*)d_in[5];
  const float* W1    = (const float*)d_in[6];
  const float* b1    = (const float*)d_in[7];
  const float* W2    = (const float*)d_in[8];
  const float* b2    = (const float*)d_in[9];
  const float* g1    = (const float*)d_in[10];
  const float* be1   = (const float*)d_in[11];
  const float* g2    = (const float*)d_in[12];
  const float* be2   = (const float*)d_in[13];
  float* out = (float*)d_out;

  u16* WqkvT  = (u16*)d_ws;                    // [3072][1024] bf16
  u16* WprojT = WqkvT + (size_t)3072 * 1024;   // [1024][1024]
  u16* W1T    = WprojT + (size_t)1024 * 1024;  // [4096][1024]
  u16* W2T    = W1T + (size_t)4096 * 1024;     // [1024][4096]
  u16* hbuf   = W2T + (size_t)1024 * 4096;     // [4096][1024]
  u16* qkv    = hbuf + (size_t)4096 * 1024;    // [4096][3072]
  u16* obuf   = qkv + (size_t)4096 * 3072;     // [4096][1024]
  float* x2   = (float*)(obuf + (size_t)4096 * 1024);  // [4096][1024] fp32
  u16* a1     = (u16*)(x2 + (size_t)4096 * 1024);      // [4096][4096]
  float* Pk   = (float*)hbuf;  // FF2 split-K partials (32 MB over hbuf+qkv)

  transpose_all_kernel<<<3072, 256, 0, stream>>>(Wq, Wk, Wv, Wproj, W1, W2,
                                                 WqkvT, WprojT, W1T, W2T);
  ln_kernel<<<4096, 256, 0, stream>>>(x, g1, be1, hbuf);
  // QKV: 256x256 8-phase (grid 12x16 = 192 blocks)
  gemm256_kernel<0><<<dim3(12, 16), 512, 0, stream>>>(hbuf, WqkvT, nullptr, nullptr, qkv, 4096, 3072, 1024);
  // attn: 8-wave QBLK=128, 256 blocks
  attn_mfma_kernel<<<dim3(8, 32), 512, 0, stream>>>(qkv, obuf);
  // proj: 128x128 2-phase dbuf
  gemm128d_kernel<2><<<dim3(8, 32), 256, 0, stream>>>(obuf, WprojT, bproj, x, x2, 4096, 1024, 1024, 1024);
  ln_kernel<<<4096, 256, 0, stream>>>(x2, g2, be2, hbuf);
  // FF1: 256x256 8-phase (must precede split-K partials overwriting hbuf)
  gemm256_kernel<1><<<dim3(16, 16), 512, 0, stream>>>(hbuf, W1T, b1, nullptr, a1, 4096, 4096, 1024);
  // FF2 split-K x2
  gemm128d_kernel<3><<<dim3(8, 32, 2), 256, 0, stream>>>(a1, W2T, nullptr, nullptr, Pk, 4096, 1024, 2048, 4096);
  combine_kernel<<<4096, 256, 0, stream>>>(Pk, x2, b2, out);
}

// Round 17
// 240.053 us; speedup vs baseline: 1.1546x; 1.0048x over previous
//
#include <hip/hip_runtime.h>
#include <stdint.h>

// Round 17: attn K/V LDS double-buffer -> ONE barrier per KV-tile:
// {write prefetched regs -> buf[t&1]; issue t+1 global loads; barrier;
// compute from buf[t&1]}. Cross-wave, writes of tile t overlap compute of
// tile t-1 (no barrier between). LDS 36->54 KB (still 1 block/CU @512thr).
// Everything else frozen from round 16.

typedef unsigned short u16;
typedef unsigned int u32;
typedef __attribute__((ext_vector_type(4))) float f32x4;
typedef __attribute__((ext_vector_type(8))) short s16x8;

__device__ __forceinline__ u16 f2bf(float f) {
  u32 u = __builtin_bit_cast(u32, f);
  u += 0x7fffu + ((u >> 16) & 1u);
  return (u16)(u >> 16);
}
__device__ __forceinline__ s16x8 ld_s16x8_a8(const u16* p) {
  union { uint2 d[2]; s16x8 v; } u;
  u.d[0] = *(const uint2*)p;
  u.d[1] = *(const uint2*)(p + 4);
  return u.v;
}
__device__ __forceinline__ void gload16(const u16* g, u16* lds_base) {
  __builtin_amdgcn_global_load_lds(
      (const __attribute__((address_space(1))) void*)g,
      (__attribute__((address_space(3))) void*)lds_base, 16, 0, 0);
}

// ---------------------------------------------------------------------------
// Fused weight transposes fp32 -> bf16^T, one launch, 3072 blocks.
// ---------------------------------------------------------------------------
__global__ __launch_bounds__(256) void transpose_all_kernel(
    const float* __restrict__ Wq, const float* __restrict__ Wk,
    const float* __restrict__ Wv, const float* __restrict__ Wproj,
    const float* __restrict__ W1, const float* __restrict__ W2,
    u16* __restrict__ WqkvT, u16* __restrict__ WprojT,
    u16* __restrict__ W1T, u16* __restrict__ W2T) {
  const int bid = blockIdx.x;
  const float* src; u16* dst; int Ccols, dstStride, r0, c0;
  if (bid < 768) {
    const int sub = bid >> 8, rem = bid & 255;
    const int z = rem >> 4, y = rem & 15;
    src = (sub == 0 ? Wq : sub == 1 ? Wk : Wv) + (size_t)z * 65536;
    dst = WqkvT + (size_t)sub * 1024 * 1024 + (size_t)z * 65536;
    Ccols = 64; dstStride = 1024; r0 = y * 64; c0 = 0;
  } else if (bid < 1024) {
    const int rem = bid - 768, xx = rem & 15, y = rem >> 4;
    src = Wproj; dst = WprojT; Ccols = 1024; dstStride = 1024;
    r0 = y * 64; c0 = xx * 64;
  } else if (bid < 2048) {
    const int rem = bid - 1024, xx = rem & 63, y = rem >> 6;
    src = W1; dst = W1T; Ccols = 4096; dstStride = 1024;
    r0 = y * 64; c0 = xx * 64;
  } else {
    const int rem = bid - 2048, xx = rem & 15, y = rem >> 4;
    src = W2; dst = W2T; Ccols = 1024; dstStride = 4096;
    r0 = y * 64; c0 = xx * 64;
  }
  __shared__ float t[64][65];
  const int tr = threadIdx.x >> 4, tc4 = (threadIdx.x & 15) * 4;
#pragma unroll
  for (int p = 0; p < 4; ++p) {
    int r = p * 16 + tr;
    float4 v = *(const float4*)(src + (size_t)(r0 + r) * Ccols + c0 + tc4);
    t[r][tc4 + 0] = v.x; t[r][tc4 + 1] = v.y;
    t[r][tc4 + 2] = v.z; t[r][tc4 + 3] = v.w;
  }
  __syncthreads();
#pragma unroll
  for (int p = 0; p < 4; ++p) {
    int c = p * 16 + tr;
    uint2 pk;
    pk.x = (u32)f2bf(t[tc4 + 0][c]) | ((u32)f2bf(t[tc4 + 1][c]) << 16);
    pk.y = (u32)f2bf(t[tc4 + 2][c]) | ((u32)f2bf(t[tc4 + 3][c]) << 16);
    *(uint2*)(dst + (size_t)(c0 + c) * dstStride + r0 + tc4) = pk;
  }
}

// ---------------------------------------------------------------------------
// LayerNorm: one block per row of 1024 fp32; out bf16.
// ---------------------------------------------------------------------------
__global__ __launch_bounds__(256) void ln_kernel(
    const float* __restrict__ x, const float* __restrict__ g,
    const float* __restrict__ be, u16* __restrict__ out) {
  const int row = blockIdx.x, tid = threadIdx.x;
  const float* xr = x + (size_t)row * 1024;
  float4 v = *(const float4*)(xr + tid * 4);
  float s = v.x + v.y + v.z + v.w;
  float q = v.x * v.x + v.y * v.y + v.z * v.z + v.w * v.w;
#pragma unroll
  for (int off = 32; off > 0; off >>= 1) {
    s += __shfl_down(s, off);
    q += __shfl_down(q, off);
  }
  __shared__ float red[8];
  const int wid = tid >> 6, lane = tid & 63;
  if (lane == 0) { red[wid] = s; red[wid + 4] = q; }
  __syncthreads();
  s = red[0] + red[1] + red[2] + red[3];
  q = red[4] + red[5] + red[6] + red[7];
  const float mu = s * (1.f / 1024.f);
  const float var = q * (1.f / 1024.f) - mu * mu;
  const float rs = rsqrtf(var + 1e-5f);
  float4 gv = *(const float4*)(g + tid * 4);
  float4 bv = *(const float4*)(be + tid * 4);
  float o0 = (v.x - mu) * rs * gv.x + bv.x;
  float o1 = (v.y - mu) * rs * gv.y + bv.y;
  float o2 = (v.z - mu) * rs * gv.z + bv.z;
  float o3 = (v.w - mu) * rs * gv.w + bv.w;
  uint2 pk;
  pk.x = (u32)f2bf(o0) | ((u32)f2bf(o1) << 16);
  pk.y = (u32)f2bf(o2) | ((u32)f2bf(o3) << 16);
  *(uint2*)(out + (size_t)row * 1024 + tid * 4) = pk;
}

// ---------------------------------------------------------------------------
// combine: out = P0 + P1 + bias + resid  (fp32)
// ---------------------------------------------------------------------------
__global__ __launch_bounds__(256) void combine_kernel(
    const float* __restrict__ P, const float* __restrict__ resid,
    const float* __restrict__ bias, float* __restrict__ out) {
  const int row = blockIdx.x, c4 = threadIdx.x * 4;
  const size_t idx = (size_t)row * 1024 + c4;
  float4 p0 = *(const float4*)(P + idx);
  float4 p1 = *(const float4*)(P + 4194304 + idx);
  float4 r  = *(const float4*)(resid + idx);
  float4 bb = *(const float4*)(bias + c4);
  float4 o;
  o.x = p0.x + p1.x + r.x + bb.x;
  o.y = p0.y + p1.y + r.y + bb.y;
  o.z = p0.z + p1.z + r.z + bb.z;
  o.w = p0.w + p1.w + r.w + bb.w;
  *(float4*)(out + idx) = o;
}

// ---------------------------------------------------------------------------
// 256x256 8-phase GEMM (T3+T4+T5) — QKV + FF1.
// ---------------------------------------------------------------------------
template <int EPI>
__global__ __launch_bounds__(512, 2) void gemm256_kernel(
    const u16* __restrict__ A, const u16* __restrict__ BT,
    const float* __restrict__ bias, const float* __restrict__ resid,
    void* __restrict__ out, int M, int N, int K) {
  __shared__ u16 lds[2][2][256][64];  // 128 KiB
  const int tid = threadIdx.x;
  const int wid = tid >> 6, lane = tid & 63;
  const int m0 = blockIdx.y * 256, n0 = blockIdx.x * 256;
  const int wr = (wid >> 2) * 128;
  const int wc = (wid & 3) * 64;
  const int l15 = lane & 15, g = lane >> 4;
  const int lr = lane >> 3;
  const int cswz = ((lane & 7) * 8) ^ (lr << 3);
  const int swz = (l15 & 7) << 3;
  const u16* Abase = A + (size_t)m0 * K;
  const u16* Bbase = BT + (size_t)n0 * K;
  const int nkt = K >> 6;

  f32x4 acc[8][4] = {};
  s16x8 bf[4][2];

  auto issue_half = [&](const u16* Xbase, int xi, int t, int hf) {
    const int b = t & 1;
    const int r0 = hf * 128 + wid * 8;
    gload16(Xbase + (size_t)(r0 + lr) * K + t * 64 + cswz, &lds[b][xi][r0][0]);
    gload16(Xbase + (size_t)(r0 + 64 + lr) * K + t * 64 + cswz, &lds[b][xi][r0 + 64][0]);
  };

  issue_half(Abase, 0, 0, 0);
  issue_half(Abase, 0, 0, 1);
  issue_half(Bbase, 1, 0, 0);
  issue_half(Bbase, 1, 0, 1);
  asm volatile("s_waitcnt vmcnt(0)" ::: "memory");
  __builtin_amdgcn_s_barrier();

  for (int i = 0; i < nkt; i += 2) {
#pragma unroll
    for (int p = 0; p < 4; ++p) {
      s16x8 af[2][2];
#pragma unroll
      for (int q = 0; q < 2; ++q) {
        const int R = wr + (2 * p + q) * 16 + l15;
#pragma unroll
        for (int h = 0; h < 2; ++h)
          af[q][h] = *(const s16x8*)(&lds[0][0][R][(h * 32 + g * 8) ^ swz]);
      }
      if (p == 0) {
#pragma unroll
        for (int n = 0; n < 4; ++n) {
          const int R = wc + n * 16 + l15;
#pragma unroll
          for (int h = 0; h < 2; ++h)
            bf[n][h] = *(const s16x8*)(&lds[0][1][R][(h * 32 + g * 8) ^ swz]);
        }
      }
      if (i + 1 < nkt) {
        if (p == 0) issue_half(Abase, 0, i + 1, 0);
        else if (p == 1) issue_half(Abase, 0, i + 1, 1);
        else if (p == 2) issue_half(Bbase, 1, i + 1, 0);
        else issue_half(Bbase, 1, i + 1, 1);
      }
      __builtin_amdgcn_s_barrier();
      asm volatile("s_waitcnt lgkmcnt(0)" ::: "memory");
      __builtin_amdgcn_sched_barrier(0);
      __builtin_amdgcn_s_setprio(1);
#pragma unroll
      for (int q = 0; q < 2; ++q)
#pragma unroll
        for (int n = 0; n < 4; ++n) {
          acc[2 * p + q][n] = __builtin_amdgcn_mfma_f32_16x16x32_bf16(af[q][0], bf[n][0], acc[2 * p + q][n], 0, 0, 0);
          acc[2 * p + q][n] = __builtin_amdgcn_mfma_f32_16x16x32_bf16(af[q][1], bf[n][1], acc[2 * p + q][n], 0, 0, 0);
        }
      __builtin_amdgcn_s_setprio(0);
      if (p == 3)
        asm volatile("s_waitcnt vmcnt(0)" ::: "memory");
      __builtin_amdgcn_s_barrier();
    }
    if (i + 1 < nkt) {
#pragma unroll
      for (int p = 0; p < 4; ++p) {
        s16x8 af[2][2];
#pragma unroll
        for (int q = 0; q < 2; ++q) {
          const int R = wr + (2 * p + q) * 16 + l15;
#pragma unroll
          for (int h = 0; h < 2; ++h)
            af[q][h] = *(const s16x8*)(&lds[1][0][R][(h * 32 + g * 8) ^ swz]);
        }
        if (p == 0) {
#pragma unroll
          for (int n = 0; n < 4; ++n) {
            const int R = wc + n * 16 + l15;
#pragma unroll
            for (int h = 0; h < 2; ++h)
              bf[n][h] = *(const s16x8*)(&lds[1][1][R][(h * 32 + g * 8) ^ swz]);
          }
        }
        if (i + 2 < nkt) {
          if (p == 0) issue_half(Abase, 0, i + 2, 0);
          else if (p == 1) issue_half(Abase, 0, i + 2, 1);
          else if (p == 2) issue_half(Bbase, 1, i + 2, 0);
          else issue_half(Bbase, 1, i + 2, 1);
        }
        __builtin_amdgcn_s_barrier();
        asm volatile("s_waitcnt lgkmcnt(0)" ::: "memory");
        __builtin_amdgcn_sched_barrier(0);
        __builtin_amdgcn_s_setprio(1);
#pragma unroll
        for (int q = 0; q < 2; ++q)
#pragma unroll
          for (int n = 0; n < 4; ++n) {
            acc[2 * p + q][n] = __builtin_amdgcn_mfma_f32_16x16x32_bf16(af[q][0], bf[n][0], acc[2 * p + q][n], 0, 0, 0);
            acc[2 * p + q][n] = __builtin_amdgcn_mfma_f32_16x16x32_bf16(af[q][1], bf[n][1], acc[2 * p + q][n], 0, 0, 0);
          }
        __builtin_amdgcn_s_setprio(0);
        if (p == 3)
          asm volatile("s_waitcnt vmcnt(0)" ::: "memory");
        __builtin_amdgcn_s_barrier();
      }
    }
  }

#pragma unroll
  for (int mi = 0; mi < 8; ++mi)
#pragma unroll
    for (int n = 0; n < 4; ++n) {
      const int col = n0 + wc + n * 16 + l15;
      float bv = (EPI >= 1) ? bias[col] : 0.f;
#pragma unroll
      for (int ii = 0; ii < 4; ++ii) {
        const int row = m0 + wr + mi * 16 + g * 4 + ii;
        float v = acc[mi][n][ii];
        if (EPI >= 1) v += bv;
        if (EPI == 1) v = fmaxf(v, 0.f);
        ((u16*)out)[(size_t)row * N + col] = f2bf(v);
      }
    }
}

// ---------------------------------------------------------------------------
// gemm128d: 128x128 2-phase dbuf. EPI 2: +bias+resid -> fp32.
// EPI 3: split-K partial (blockIdx.z selects K-chunk + output slab).
// ---------------------------------------------------------------------------
template <int EPI>
__global__ __launch_bounds__(256, 2) void gemm128d_kernel(
    const u16* __restrict__ A, const u16* __restrict__ BT,
    const float* __restrict__ bias, const float* __restrict__ resid,
    void* __restrict__ out, int M, int N, int K, int lda) {
  __shared__ u16 lds[2][2][128][64];  // 64 KiB
  const int tid = threadIdx.x;
  const int wid = tid >> 6, lane = tid & 63;
  const int m0 = blockIdx.y * 128, n0 = blockIdx.x * 128;
  const int wr = (wid >> 1) * 64, wc = (wid & 1) * 64;
  const int l15 = lane & 15, g = lane >> 4;
  const int lr = lane >> 3;
  const int cswz = ((lane & 7) * 8) ^ (lr << 3);
  const int swz = (l15 & 7) << 3;
  const int nkt = K >> 6;
  f32x4 acc[4][4] = {};

  if (EPI == 3) {
    const int koff = (int)blockIdx.z * K;
    A += koff; BT += koff;
  }

  auto stage = [&](int bsel, int t) {
#pragma unroll
    for (int p = 0; p < 4; ++p) {
      const int row = (p * 4 + wid) * 8;
      gload16(A + (size_t)(m0 + row + lr) * lda + t * 64 + cswz, &lds[bsel][0][row][0]);
    }
#pragma unroll
    for (int p = 0; p < 4; ++p) {
      const int row = (p * 4 + wid) * 8;
      gload16(BT + (size_t)(n0 + row + lr) * lda + t * 64 + cswz, &lds[bsel][1][row][0]);
    }
  };

  stage(0, 0);
  __syncthreads();

  int cur = 0;
  for (int i = 0; i < nkt; ++i) {
    if (i + 1 < nkt) stage(cur ^ 1, i + 1);
    s16x8 af[4][2], bf[4][2];
#pragma unroll
    for (int m = 0; m < 4; ++m) {
      const int R = wr + m * 16 + l15;
#pragma unroll
      for (int h = 0; h < 2; ++h)
        af[m][h] = *(const s16x8*)(&lds[cur][0][R][(h * 32 + g * 8) ^ swz]);
    }
#pragma unroll
    for (int n = 0; n < 4; ++n) {
      const int R = wc + n * 16 + l15;
#pragma unroll
      for (int h = 0; h < 2; ++h)
        bf[n][h] = *(const s16x8*)(&lds[cur][1][R][(h * 32 + g * 8) ^ swz]);
    }
    __builtin_amdgcn_s_setprio(1);
#pragma unroll
    for (int m = 0; m < 4; ++m)
#pragma unroll
      for (int n = 0; n < 4; ++n) {
        acc[m][n] = __builtin_amdgcn_mfma_f32_16x16x32_bf16(af[m][0], bf[n][0], acc[m][n], 0, 0, 0);
        acc[m][n] = __builtin_amdgcn_mfma_f32_16x16x32_bf16(af[m][1], bf[n][1], acc[m][n], 0, 0, 0);
      }
    __builtin_amdgcn_s_setprio(0);
    __syncthreads();
    cur ^= 1;
  }

  float* outf = (float*)out;
  if (EPI == 3) outf += (size_t)blockIdx.z * M * N;
#pragma unroll
  for (int m = 0; m < 4; ++m) {
#pragma unroll
    for (int n = 0; n < 4; ++n) {
      const int col = n0 + wc + n * 16 + l15;
      float bv = (EPI == 1 || EPI == 2) ? bias[col] : 0.f;
#pragma unroll
      for (int i = 0; i < 4; ++i) {
        const int row = m0 + wr + m * 16 + g * 4 + i;
        float v = acc[m][n][i];
        if (EPI == 1 || EPI == 2) v += bv;
        if (EPI == 1) v = fmaxf(v, 0.f);
        if (EPI == 2) {
          v += resid[(size_t)row * N + col];
          outf[(size_t)row * N + col] = v;
        } else if (EPI == 3) {
          outf[(size_t)row * N + col] = v;
        } else {
          ((u16*)out)[(size_t)row * N + col] = f2bf(v);
        }
      }
    }
  }
}

// ---------------------------------------------------------------------------
// MFMA causal flash attention, 8-wave QBLK=128, K/V LDS DOUBLE-BUFFER:
// one barrier per KV-tile. Per tile: {write prefetched regs -> buf[t&1];
// issue t+1 global loads; barrier; compute}. Writes of tile t overlap other
// waves' compute of tile t-1. Paired {15-bx, bx}, uniform 34 tiles/block.
// T13 defer-max.
// ---------------------------------------------------------------------------
__global__ __launch_bounds__(512) void attn_mfma_kernel(
    const u16* __restrict__ qkv, u16* __restrict__ o) {
  __shared__ u16 sK[2][64][72];   // [buf][s][d]
  __shared__ u16 sVt[2][64][68];  // [buf][d][s]
  __shared__ u16 sP[8][16][72];   // per-wave P strip
  const int tid = threadIdx.x;
  const int b = blockIdx.y >> 4, h = blockIdx.y & 15;
  const int w = tid >> 6, lane = tid & 63;
  const int l15 = lane & 15, g = lane >> 4;
  const float c = 0.125f * 1.4426950408889634f;  // scale * log2(e)
  const int ks_r = tid >> 3, ks_c = (tid & 7) * 8;   // K: 512 x 16B
  const int vs_s = tid & 63, vs_d = (tid >> 6) * 8;  // V^T: 512 x 8 u16
  const u16* kbase = qkv + (size_t)(b * 2048) * 3072 + 1024 + h * 64;
  const u16* vbase = kbase + 1024;

#pragma unroll 1
  for (int pass = 0; pass < 2; ++pass) {
    const int qb = pass == 0 ? (15 - (int)blockIdx.x) : (int)blockIdx.x;
    const int qw = qb * 128 + w * 16;  // wave q base

    const size_t qrow = (size_t)(b * 2048 + qw + l15);
    s16x8 qf0 = *(const s16x8*)(qkv + qrow * 3072 + h * 64 + g * 8);
    s16x8 qf1 = *(const s16x8*)(qkv + qrow * 3072 + h * 64 + 32 + g * 8);

    f32x4 oacc[4] = {};
    float mrow[4] = {-1e30f, -1e30f, -1e30f, -1e30f};
    float lrow[4] = {0.f, 0.f, 0.f, 0.f};  // per-lane partial; reduced at end

    const int nt = 2 * qb + 2;
    uint4 kr0, vr0;
    {
      const u16* kp = kbase + (size_t)(ks_r)*3072 + ks_c;
      kr0 = *(const uint4*)kp;
      const u16* vp = vbase + (size_t)(vs_s)*3072 + vs_d;
      vr0 = *(const uint4*)vp;
    }
    for (int t = 0; t < nt; ++t) {
      const int pb = t & 1;
      // write tile t's prefetched regs into buf[pb]; last reads of buf[pb]
      // (compute t-2) are fenced by the barrier inside iteration t-1.
      *(uint4*)(&sK[pb][ks_r][ks_c]) = kr0;
      {
        union { uint4 q4; u16 e[8]; } va;
        va.q4 = vr0;
#pragma unroll
        for (int j = 0; j < 8; ++j) sVt[pb][vs_d + j][vs_s] = va.e[j];
      }
      if (t + 1 < nt) {  // T14: issue next tile's global loads
        const u16* kp = kbase + (size_t)((t + 1) * 64 + ks_r) * 3072 + ks_c;
        kr0 = *(const uint4*)kp;
        const u16* vp = vbase + (size_t)((t + 1) * 64 + vs_s) * 3072 + vs_d;
        vr0 = *(const uint4*)vp;
      }
      __syncthreads();  // buf[pb] visible to all; ONLY barrier this tile

      f32x4 st[4];
#pragma unroll
      for (int n = 0; n < 4; ++n) {
        s16x8 k0 = *(const s16x8*)(&sK[pb][n * 16 + l15][g * 8]);
        s16x8 k1 = *(const s16x8*)(&sK[pb][n * 16 + l15][32 + g * 8]);
        f32x4 a = {};
        a = __builtin_amdgcn_mfma_f32_16x16x32_bf16(qf0, k0, a, 0, 0, 0);
        a = __builtin_amdgcn_mfma_f32_16x16x32_bf16(qf1, k1, a, 0, 0, 0);
        st[n] = a;
      }
      if (t >= 2 * qb) {  // diagonal spans the last two tiles (absolute idx)
#pragma unroll
        for (int n = 0; n < 4; ++n)
#pragma unroll
          for (int i = 0; i < 4; ++i) {
            const int s_abs = t * 64 + n * 16 + l15;
            const int q_abs = qw + 4 * g + i;
            if (s_abs > q_abs) st[n][i] = -1e30f;
          }
      }
      float pm[4];
#pragma unroll
      for (int i = 0; i < 4; ++i)
        pm[i] = fmaxf(fmaxf(st[0][i], st[1][i]), fmaxf(st[2][i], st[3][i]));
#pragma unroll
      for (int msk = 1; msk < 16; msk <<= 1)
#pragma unroll
        for (int i = 0; i < 4; ++i) pm[i] = fmaxf(pm[i], __shfl_xor(pm[i], msk));
      bool need = false;  // T13 defer-max
#pragma unroll
      for (int i = 0; i < 4; ++i) need = need || (pm[i] > mrow[i] + 12.f);
      if (__any(need)) {
#pragma unroll
        for (int i = 0; i < 4; ++i) {
          const float mnew = fmaxf(mrow[i], pm[i]);
          const float corr = exp2f((mrow[i] - mnew) * c);
          mrow[i] = mnew;
          lrow[i] *= corr;
#pragma unroll
          for (int dt = 0; dt < 4; ++dt) oacc[dt][i] *= corr;
        }
      }
      float p[4][4];
#pragma unroll
      for (int n = 0; n < 4; ++n)
#pragma unroll
        for (int i = 0; i < 4; ++i) p[n][i] = exp2f((st[n][i] - mrow[i]) * c);
#pragma unroll
      for (int i = 0; i < 4; ++i)
        lrow[i] += (p[0][i] + p[1][i]) + (p[2][i] + p[3][i]);
#pragma unroll
      for (int n = 0; n < 4; ++n)
#pragma unroll
        for (int i = 0; i < 4; ++i)
          sP[w][4 * g + i][n * 16 + l15] = f2bf(p[n][i]);
      s16x8 pf0 = *(const s16x8*)(&sP[w][l15][g * 8]);
      s16x8 pf1 = *(const s16x8*)(&sP[w][l15][32 + g * 8]);
#pragma unroll
      for (int dt = 0; dt < 4; ++dt) {
        s16x8 vf0 = ld_s16x8_a8(&sVt[pb][dt * 16 + l15][g * 8]);
        s16x8 vf1 = ld_s16x8_a8(&sVt[pb][dt * 16 + l15][32 + g * 8]);
        oacc[dt] = __builtin_amdgcn_mfma_f32_16x16x32_bf16(pf0, vf0, oacc[dt], 0, 0, 0);
        oacc[dt] = __builtin_amdgcn_mfma_f32_16x16x32_bf16(pf1, vf1, oacc[dt], 0, 0, 0);
      }
    }

#pragma unroll
    for (int msk = 1; msk < 16; msk <<= 1)
#pragma unroll
      for (int i = 0; i < 4; ++i) lrow[i] += __shfl_xor(lrow[i], msk);
    float inv[4];
#pragma unroll
    for (int i = 0; i < 4; ++i) inv[i] = 1.f / lrow[i];
#pragma unroll
    for (int dt = 0; dt < 4; ++dt)
#pragma unroll
      for (int i = 0; i < 4; ++i) {
        const size_t row = (size_t)(b * 2048 + qw + 4 * g + i);
        o[row * 1024 + h * 64 + dt * 16 + l15] = f2bf(oacc[dt][i] * inv[i]);
      }
    // pass boundary: ensure all waves finished reading buf state before the
    // next pass's first write (parity restarts at 0).
    __syncthreads();
  }
}

// ---------------------------------------------------------------------------
extern "C" void kernel_launch(void* const* d_in, const int* in_sizes, int n_in,
                              void* d_out, int out_size, void* d_ws, size_t ws_size,
                              hipStream_t stream) {
  const float* x     = (const float*)d_in[0];
  const float* Wq    = (const float*)d_in[1];
  const float* Wk    = (const float*)d_in[2];
  const float* Wv    = (const float*)d_in[3];
  const float* Wproj = (const float*)d_in[4];
  const float* bproj = (const float*)d_in[5];
  const float* W1    = (const float*)d_in[6];
  const float* b1    = (const float*)d_in[7];
  const float* W2    = (const float*)d_in[8];
  const float* b2    = (const float*)d_in[9];
  const float* g1    = (const float*)d_in[10];
  const float* be1   = (const float*)d_in[11];
  const float* g2    = (const float*)d_in[12];
  const float* be2   = (const float*)d_in[13];
  float* out = (float*)d_out;

  u16* WqkvT  = (u16*)d_ws;                    // [3072][1024] bf16
  u16* WprojT = WqkvT + (size_t)3072 * 1024;   // [1024][1024]
  u16* W1T    = WprojT + (size_t)1024 * 1024;  // [4096][1024]
  u16* W2T    = W1T + (size_t)4096 * 1024;     // [1024][4096]
  u16* hbuf   = W2T + (size_t)1024 * 4096;     // [4096][1024]
  u16* qkv    = hbuf + (size_t)4096 * 1024;    // [4096][3072]
  u16* obuf   = qkv + (size_t)4096 * 3072;     // [4096][1024]
  float* x2   = (float*)(obuf + (size_t)4096 * 1024);  // [4096][1024] fp32
  u16* a1     = (u16*)(x2 + (size_t)4096 * 1024);      // [4096][4096]
  float* Pk   = (float*)hbuf;  // FF2 split-K partials (32 MB over hbuf+qkv)

  transpose_all_kernel<<<3072, 256, 0, stream>>>(Wq, Wk, Wv, Wproj, W1, W2,
                                                 WqkvT, WprojT, W1T, W2T);
  ln_kernel<<<4096, 256, 0, stream>>>(x, g1, be1, hbuf);
  gemm256_kernel<0><<<dim3(12, 16), 512, 0, stream>>>(hbuf, WqkvT, nullptr, nullptr, qkv, 4096, 3072, 1024);
  attn_mfma_kernel<<<dim3(8, 32), 512, 0, stream>>>(qkv, obuf);
  gemm128d_kernel<2><<<dim3(8, 32), 256, 0, stream>>>(obuf, WprojT, bproj, x, x2, 4096, 1024, 1024, 1024);
  ln_kernel<<<4096, 256, 0, stream>>>(x2, g2, be2, hbuf);
  gemm256_kernel<1><<<dim3(16, 16), 512, 0, stream>>>(hbuf, W1T, b1, nullptr, a1, 4096, 4096, 1024);
  gemm128d_kernel<3><<<dim3(8, 32, 2), 256, 0, stream>>>(a1, W2T, nullptr, nullptr, Pk, 4096, 1024, 2048, 4096);
  combine_kernel<<<4096, 256, 0, stream>>>(Pk, x2, b2, out);
}

// Round 20
// 236.271 us; speedup vs baseline: 1.1731x; 1.0160x over previous
//
#include <hip/hip_runtime.h>
#include <stdint.h>

// Round 20 == round 18 kernel resubmitted verbatim (2nd retry): rounds 18-19
// both died with UnresponsiveContainer (infra, same stale container as the
// r4-r6 episode) before any compile/launch. The attn 512-block (2 blocks/CU)
// change is still unmeasured; no code changes until one clean data point.
//
// Round 18: attn grid 256 -> 512 blocks (2 blocks/CU). The r17 kernel was
// latency-bound at 1 block/CU BY CONSTRUCTION (grid==CU count); VGPR 56 /
// LDS 54KB allow 2 blocks/CU. Pairing moves from in-kernel pass-loop to the
// r11 anti-correlated block->qb mapping (same-CU pair sums to uniform 34
// tiles). Kernel body (dbuf, one barrier, T13/T14) unchanged. All other
// kernels frozen from round 17.

typedef unsigned short u16;
typedef unsigned int u32;
typedef __attribute__((ext_vector_type(4))) float f32x4;
typedef __attribute__((ext_vector_type(8))) short s16x8;

__device__ __forceinline__ u16 f2bf(float f) {
  u32 u = __builtin_bit_cast(u32, f);
  u += 0x7fffu + ((u >> 16) & 1u);
  return (u16)(u >> 16);
}
__device__ __forceinline__ s16x8 ld_s16x8_a8(const u16* p) {
  union { uint2 d[2]; s16x8 v; } u;
  u.d[0] = *(const uint2*)p;
  u.d[1] = *(const uint2*)(p + 4);
  return u.v;
}
__device__ __forceinline__ void gload16(const u16* g, u16* lds_base) {
  __builtin_amdgcn_global_load_lds(
      (const __attribute__((address_space(1))) void*)g,
      (__attribute__((address_space(3))) void*)lds_base, 16, 0, 0);
}

// ---------------------------------------------------------------------------
// Fused weight transposes fp32 -> bf16^T, one launch, 3072 blocks.
// ---------------------------------------------------------------------------
__global__ __launch_bounds__(256) void transpose_all_kernel(
    const float* __restrict__ Wq, const float* __restrict__ Wk,
    const float* __restrict__ Wv, const float* __restrict__ Wproj,
    const float* __restrict__ W1, const float* __restrict__ W2,
    u16* __restrict__ WqkvT, u16* __restrict__ WprojT,
    u16* __restrict__ W1T, u16* __restrict__ W2T) {
  const int bid = blockIdx.x;
  const float* src; u16* dst; int Ccols, dstStride, r0, c0;
  if (bid < 768) {
    const int sub = bid >> 8, rem = bid & 255;
    const int z = rem >> 4, y = rem & 15;
    src = (sub == 0 ? Wq : sub == 1 ? Wk : Wv) + (size_t)z * 65536;
    dst = WqkvT + (size_t)sub * 1024 * 1024 + (size_t)z * 65536;
    Ccols = 64; dstStride = 1024; r0 = y * 64; c0 = 0;
  } else if (bid < 1024) {
    const int rem = bid - 768, xx = rem & 15, y = rem >> 4;
    src = Wproj; dst = WprojT; Ccols = 1024; dstStride = 1024;
    r0 = y * 64; c0 = xx * 64;
  } else if (bid < 2048) {
    const int rem = bid - 1024, xx = rem & 63, y = rem >> 6;
    src = W1; dst = W1T; Ccols = 4096; dstStride = 1024;
    r0 = y * 64; c0 = xx * 64;
  } else {
    const int rem = bid - 2048, xx = rem & 15, y = rem >> 4;
    src = W2; dst = W2T; Ccols = 1024; dstStride = 4096;
    r0 = y * 64; c0 = xx * 64;
  }
  __shared__ float t[64][65];
  const int tr = threadIdx.x >> 4, tc4 = (threadIdx.x & 15) * 4;
#pragma unroll
  for (int p = 0; p < 4; ++p) {
    int r = p * 16 + tr;
    float4 v = *(const float4*)(src + (size_t)(r0 + r) * Ccols + c0 + tc4);
    t[r][tc4 + 0] = v.x; t[r][tc4 + 1] = v.y;
    t[r][tc4 + 2] = v.z; t[r][tc4 + 3] = v.w;
  }
  __syncthreads();
#pragma unroll
  for (int p = 0; p < 4; ++p) {
    int c = p * 16 + tr;
    uint2 pk;
    pk.x = (u32)f2bf(t[tc4 + 0][c]) | ((u32)f2bf(t[tc4 + 1][c]) << 16);
    pk.y = (u32)f2bf(t[tc4 + 2][c]) | ((u32)f2bf(t[tc4 + 3][c]) << 16);
    *(uint2*)(dst + (size_t)(c0 + c) * dstStride + r0 + tc4) = pk;
  }
}

// ---------------------------------------------------------------------------
// LayerNorm: one block per row of 1024 fp32; out bf16.
// ---------------------------------------------------------------------------
__global__ __launch_bounds__(256) void ln_kernel(
    const float* __restrict__ x, const float* __restrict__ g,
    const float* __restrict__ be, u16* __restrict__ out) {
  const int row = blockIdx.x, tid = threadIdx.x;
  const float* xr = x + (size_t)row * 1024;
  float4 v = *(const float4*)(xr + tid * 4);
  float s = v.x + v.y + v.z + v.w;
  float q = v.x * v.x + v.y * v.y + v.z * v.z + v.w * v.w;
#pragma unroll
  for (int off = 32; off > 0; off >>= 1) {
    s += __shfl_down(s, off);
    q += __shfl_down(q, off);
  }
  __shared__ float red[8];
  const int wid = tid >> 6, lane = tid & 63;
  if (lane == 0) { red[wid] = s; red[wid + 4] = q; }
  __syncthreads();
  s = red[0] + red[1] + red[2] + red[3];
  q = red[4] + red[5] + red[6] + red[7];
  const float mu = s * (1.f / 1024.f);
  const float var = q * (1.f / 1024.f) - mu * mu;
  const float rs = rsqrtf(var + 1e-5f);
  float4 gv = *(const float4*)(g + tid * 4);
  float4 bv = *(const float4*)(be + tid * 4);
  float o0 = (v.x - mu) * rs * gv.x + bv.x;
  float o1 = (v.y - mu) * rs * gv.y + bv.y;
  float o2 = (v.z - mu) * rs * gv.z + bv.z;
  float o3 = (v.w - mu) * rs * gv.w + bv.w;
  uint2 pk;
  pk.x = (u32)f2bf(o0) | ((u32)f2bf(o1) << 16);
  pk.y = (u32)f2bf(o2) | ((u32)f2bf(o3) << 16);
  *(uint2*)(out + (size_t)row * 1024 + tid * 4) = pk;
}

// ---------------------------------------------------------------------------
// combine: out = P0 + P1 + bias + resid  (fp32)
// ---------------------------------------------------------------------------
__global__ __launch_bounds__(256) void combine_kernel(
    const float* __restrict__ P, const float* __restrict__ resid,
    const float* __restrict__ bias, float* __restrict__ out) {
  const int row = blockIdx.x, c4 = threadIdx.x * 4;
  const size_t idx = (size_t)row * 1024 + c4;
  float4 p0 = *(const float4*)(P + idx);
  float4 p1 = *(const float4*)(P + 4194304 + idx);
  float4 r  = *(const float4*)(resid + idx);
  float4 bb = *(const float4*)(bias + c4);
  float4 o;
  o.x = p0.x + p1.x + r.x + bb.x;
  o.y = p0.y + p1.y + r.y + bb.y;
  o.z = p0.z + p1.z + r.z + bb.z;
  o.w = p0.w + p1.w + r.w + bb.w;
  *(float4*)(out + idx) = o;
}

// ---------------------------------------------------------------------------
// 256x256 8-phase GEMM (T3+T4+T5) — QKV + FF1.
// ---------------------------------------------------------------------------
template <int EPI>
__global__ __launch_bounds__(512, 2) void gemm256_kernel(
    const u16* __restrict__ A, const u16* __restrict__ BT,
    const float* __restrict__ bias, const float* __restrict__ resid,
    void* __restrict__ out, int M, int N, int K) {
  __shared__ u16 lds[2][2][256][64];  // 128 KiB
  const int tid = threadIdx.x;
  const int wid = tid >> 6, lane = tid & 63;
  const int m0 = blockIdx.y * 256, n0 = blockIdx.x * 256;
  const int wr = (wid >> 2) * 128;
  const int wc = (wid & 3) * 64;
  const int l15 = lane & 15, g = lane >> 4;
  const int lr = lane >> 3;
  const int cswz = ((lane & 7) * 8) ^ (lr << 3);
  const int swz = (l15 & 7) << 3;
  const u16* Abase = A + (size_t)m0 * K;
  const u16* Bbase = BT + (size_t)n0 * K;
  const int nkt = K >> 6;

  f32x4 acc[8][4] = {};
  s16x8 bf[4][2];

  auto issue_half = [&](const u16* Xbase, int xi, int t, int hf) {
    const int b = t & 1;
    const int r0 = hf * 128 + wid * 8;
    gload16(Xbase + (size_t)(r0 + lr) * K + t * 64 + cswz, &lds[b][xi][r0][0]);
    gload16(Xbase + (size_t)(r0 + 64 + lr) * K + t * 64 + cswz, &lds[b][xi][r0 + 64][0]);
  };

  issue_half(Abase, 0, 0, 0);
  issue_half(Abase, 0, 0, 1);
  issue_half(Bbase, 1, 0, 0);
  issue_half(Bbase, 1, 0, 1);
  asm volatile("s_waitcnt vmcnt(0)" ::: "memory");
  __builtin_amdgcn_s_barrier();

  for (int i = 0; i < nkt; i += 2) {
#pragma unroll
    for (int p = 0; p < 4; ++p) {
      s16x8 af[2][2];
#pragma unroll
      for (int q = 0; q < 2; ++q) {
        const int R = wr + (2 * p + q) * 16 + l15;
#pragma unroll
        for (int h = 0; h < 2; ++h)
          af[q][h] = *(const s16x8*)(&lds[0][0][R][(h * 32 + g * 8) ^ swz]);
      }
      if (p == 0) {
#pragma unroll
        for (int n = 0; n < 4; ++n) {
          const int R = wc + n * 16 + l15;
#pragma unroll
          for (int h = 0; h < 2; ++h)
            bf[n][h] = *(const s16x8*)(&lds[0][1][R][(h * 32 + g * 8) ^ swz]);
        }
      }
      if (i + 1 < nkt) {
        if (p == 0) issue_half(Abase, 0, i + 1, 0);
        else if (p == 1) issue_half(Abase, 0, i + 1, 1);
        else if (p == 2) issue_half(Bbase, 1, i + 1, 0);
        else issue_half(Bbase, 1, i + 1, 1);
      }
      __builtin_amdgcn_s_barrier();
      asm volatile("s_waitcnt lgkmcnt(0)" ::: "memory");
      __builtin_amdgcn_sched_barrier(0);
      __builtin_amdgcn_s_setprio(1);
#pragma unroll
      for (int q = 0; q < 2; ++q)
#pragma unroll
        for (int n = 0; n < 4; ++n) {
          acc[2 * p + q][n] = __builtin_amdgcn_mfma_f32_16x16x32_bf16(af[q][0], bf[n][0], acc[2 * p + q][n], 0, 0, 0);
          acc[2 * p + q][n] = __builtin_amdgcn_mfma_f32_16x16x32_bf16(af[q][1], bf[n][1], acc[2 * p + q][n], 0, 0, 0);
        }
      __builtin_amdgcn_s_setprio(0);
      if (p == 3)
        asm volatile("s_waitcnt vmcnt(0)" ::: "memory");
      __builtin_amdgcn_s_barrier();
    }
    if (i + 1 < nkt) {
#pragma unroll
      for (int p = 0; p < 4; ++p) {
        s16x8 af[2][2];
#pragma unroll
        for (int q = 0; q < 2; ++q) {
          const int R = wr + (2 * p + q) * 16 + l15;
#pragma unroll
          for (int h = 0; h < 2; ++h)
            af[q][h] = *(const s16x8*)(&lds[1][0][R][(h * 32 + g * 8) ^ swz]);
        }
        if (p == 0) {
#pragma unroll
          for (int n = 0; n < 4; ++n) {
            const int R = wc + n * 16 + l15;
#pragma unroll
            for (int h = 0; h < 2; ++h)
              bf[n][h] = *(const s16x8*)(&lds[1][1][R][(h * 32 + g * 8) ^ swz]);
          }
        }
        if (i + 2 < nkt) {
          if (p == 0) issue_half(Abase, 0, i + 2, 0);
          else if (p == 1) issue_half(Abase, 0, i + 2, 1);
          else if (p == 2) issue_half(Bbase, 1, i + 2, 0);
          else issue_half(Bbase, 1, i + 2, 1);
        }
        __builtin_amdgcn_s_barrier();
        asm volatile("s_waitcnt lgkmcnt(0)" ::: "memory");
        __builtin_amdgcn_sched_barrier(0);
        __builtin_amdgcn_s_setprio(1);
#pragma unroll
        for (int q = 0; q < 2; ++q)
#pragma unroll
          for (int n = 0; n < 4; ++n) {
            acc[2 * p + q][n] = __builtin_amdgcn_mfma_f32_16x16x32_bf16(af[q][0], bf[n][0], acc[2 * p + q][n], 0, 0, 0);
            acc[2 * p + q][n] = __builtin_amdgcn_mfma_f32_16x16x32_bf16(af[q][1], bf[n][1], acc[2 * p + q][n], 0, 0, 0);
          }
        __builtin_amdgcn_s_setprio(0);
        if (p == 3)
          asm volatile("s_waitcnt vmcnt(0)" ::: "memory");
        __builtin_amdgcn_s_barrier();
      }
    }
  }

#pragma unroll
  for (int mi = 0; mi < 8; ++mi)
#pragma unroll
    for (int n = 0; n < 4; ++n) {
      const int col = n0 + wc + n * 16 + l15;
      float bv = (EPI >= 1) ? bias[col] : 0.f;
#pragma unroll
      for (int ii = 0; ii < 4; ++ii) {
        const int row = m0 + wr + mi * 16 + g * 4 + ii;
        float v = acc[mi][n][ii];
        if (EPI >= 1) v += bv;
        if (EPI == 1) v = fmaxf(v, 0.f);
        ((u16*)out)[(size_t)row * N + col] = f2bf(v);
      }
    }
}

// ---------------------------------------------------------------------------
// gemm128d: 128x128 2-phase dbuf. EPI 2: +bias+resid -> fp32.
// EPI 3: split-K partial (blockIdx.z selects K-chunk + output slab).
// ---------------------------------------------------------------------------
template <int EPI>
__global__ __launch_bounds__(256, 2) void gemm128d_kernel(
    const u16* __restrict__ A, const u16* __restrict__ BT,
    const float* __restrict__ bias, const float* __restrict__ resid,
    void* __restrict__ out, int M, int N, int K, int lda) {
  __shared__ u16 lds[2][2][128][64];  // 64 KiB
  const int tid = threadIdx.x;
  const int wid = tid >> 6, lane = tid & 63;
  const int m0 = blockIdx.y * 128, n0 = blockIdx.x * 128;
  const int wr = (wid >> 1) * 64, wc = (wid & 1) * 64;
  const int l15 = lane & 15, g = lane >> 4;
  const int lr = lane >> 3;
  const int cswz = ((lane & 7) * 8) ^ (lr << 3);
  const int swz = (l15 & 7) << 3;
  const int nkt = K >> 6;
  f32x4 acc[4][4] = {};

  if (EPI == 3) {
    const int koff = (int)blockIdx.z * K;
    A += koff; BT += koff;
  }

  auto stage = [&](int bsel, int t) {
#pragma unroll
    for (int p = 0; p < 4; ++p) {
      const int row = (p * 4 + wid) * 8;
      gload16(A + (size_t)(m0 + row + lr) * lda + t * 64 + cswz, &lds[bsel][0][row][0]);
    }
#pragma unroll
    for (int p = 0; p < 4; ++p) {
      const int row = (p * 4 + wid) * 8;
      gload16(BT + (size_t)(n0 + row + lr) * lda + t * 64 + cswz, &lds[bsel][1][row][0]);
    }
  };

  stage(0, 0);
  __syncthreads();

  int cur = 0;
  for (int i = 0; i < nkt; ++i) {
    if (i + 1 < nkt) stage(cur ^ 1, i + 1);
    s16x8 af[4][2], bf[4][2];
#pragma unroll
    for (int m = 0; m < 4; ++m) {
      const int R = wr + m * 16 + l15;
#pragma unroll
      for (int h = 0; h < 2; ++h)
        af[m][h] = *(const s16x8*)(&lds[cur][0][R][(h * 32 + g * 8) ^ swz]);
    }
#pragma unroll
    for (int n = 0; n < 4; ++n) {
      const int R = wc + n * 16 + l15;
#pragma unroll
      for (int h = 0; h < 2; ++h)
        bf[n][h] = *(const s16x8*)(&lds[cur][1][R][(h * 32 + g * 8) ^ swz]);
    }
    __builtin_amdgcn_s_setprio(1);
#pragma unroll
    for (int m = 0; m < 4; ++m)
#pragma unroll
      for (int n = 0; n < 4; ++n) {
        acc[m][n] = __builtin_amdgcn_mfma_f32_16x16x32_bf16(af[m][0], bf[n][0], acc[m][n], 0, 0, 0);
        acc[m][n] = __builtin_amdgcn_mfma_f32_16x16x32_bf16(af[m][1], bf[n][1], acc[m][n], 0, 0, 0);
      }
    __builtin_amdgcn_s_setprio(0);
    __syncthreads();
    cur ^= 1;
  }

  float* outf = (float*)out;
  if (EPI == 3) outf += (size_t)blockIdx.z * M * N;
#pragma unroll
  for (int m = 0; m < 4; ++m) {
#pragma unroll
    for (int n = 0; n < 4; ++n) {
      const int col = n0 + wc + n * 16 + l15;
      float bv = (EPI == 1 || EPI == 2) ? bias[col] : 0.f;
#pragma unroll
      for (int i = 0; i < 4; ++i) {
        const int row = m0 + wr + m * 16 + g * 4 + i;
        float v = acc[m][n][i];
        if (EPI == 1 || EPI == 2) v += bv;
        if (EPI == 1) v = fmaxf(v, 0.f);
        if (EPI == 2) {
          v += resid[(size_t)row * N + col];
          outf[(size_t)row * N + col] = v;
        } else if (EPI == 3) {
          outf[(size_t)row * N + col] = v;
        } else {
          ((u16*)out)[(size_t)row * N + col] = f2bf(v);
        }
      }
    }
  }
}

// ---------------------------------------------------------------------------
// MFMA causal flash attention, 8-wave QBLK=128, K/V dbuf, one barrier/tile.
// 1-D grid of 512 blocks (2/CU): lid<256 -> qb=15-((lid>>5)&7) (heavy),
// lid>=256 -> qb=(lid-256)>>5 (light, anti-correlated on the same CU);
// bh=lid&31. T13 defer-max; T14 reg-prefetch.
// ---------------------------------------------------------------------------
__global__ __launch_bounds__(512) void attn_mfma_kernel(
    const u16* __restrict__ qkv, u16* __restrict__ o) {
  __shared__ u16 sK[2][64][72];   // [buf][s][d]
  __shared__ u16 sVt[2][64][68];  // [buf][d][s]
  __shared__ u16 sP[8][16][72];   // per-wave P strip
  const int tid = threadIdx.x;
  const int lid = (int)blockIdx.x;
  const int bh = lid & 31;
  const int qb = (lid < 256) ? (15 - ((lid >> 5) & 7)) : ((lid - 256) >> 5);
  const int b = bh >> 4, h = bh & 15;
  const int w = tid >> 6, lane = tid & 63;
  const int l15 = lane & 15, g = lane >> 4;
  const float c = 0.125f * 1.4426950408889634f;  // scale * log2(e)
  const int ks_r = tid >> 3, ks_c = (tid & 7) * 8;   // K: 512 x 16B
  const int vs_s = tid & 63, vs_d = (tid >> 6) * 8;  // V^T: 512 x 8 u16
  const u16* kbase = qkv + (size_t)(b * 2048) * 3072 + 1024 + h * 64;
  const u16* vbase = kbase + 1024;
  const int qw = qb * 128 + w * 16;  // wave q base

  const size_t qrow = (size_t)(b * 2048 + qw + l15);
  s16x8 qf0 = *(const s16x8*)(qkv + qrow * 3072 + h * 64 + g * 8);
  s16x8 qf1 = *(const s16x8*)(qkv + qrow * 3072 + h * 64 + 32 + g * 8);

  f32x4 oacc[4] = {};
  float mrow[4] = {-1e30f, -1e30f, -1e30f, -1e30f};
  float lrow[4] = {0.f, 0.f, 0.f, 0.f};  // per-lane partial; reduced at end

  const int nt = 2 * qb + 2;
  uint4 kr0, vr0;
  {
    const u16* kp = kbase + (size_t)(ks_r)*3072 + ks_c;
    kr0 = *(const uint4*)kp;
    const u16* vp = vbase + (size_t)(vs_s)*3072 + vs_d;
    vr0 = *(const uint4*)vp;
  }
  for (int t = 0; t < nt; ++t) {
    const int pb = t & 1;
    // write tile t's prefetched regs into buf[pb]; last reads of buf[pb]
    // (compute t-2) are fenced by the barrier inside iteration t-1.
    *(uint4*)(&sK[pb][ks_r][ks_c]) = kr0;
    {
      union { uint4 q4; u16 e[8]; } va;
      va.q4 = vr0;
#pragma unroll
      for (int j = 0; j < 8; ++j) sVt[pb][vs_d + j][vs_s] = va.e[j];
    }
    if (t + 1 < nt) {  // T14: issue next tile's global loads
      const u16* kp = kbase + (size_t)((t + 1) * 64 + ks_r) * 3072 + ks_c;
      kr0 = *(const uint4*)kp;
      const u16* vp = vbase + (size_t)((t + 1) * 64 + vs_s) * 3072 + vs_d;
      vr0 = *(const uint4*)vp;
    }
    __syncthreads();  // buf[pb] visible to all; ONLY barrier this tile

    f32x4 st[4];
#pragma unroll
    for (int n = 0; n < 4; ++n) {
      s16x8 k0 = *(const s16x8*)(&sK[pb][n * 16 + l15][g * 8]);
      s16x8 k1 = *(const s16x8*)(&sK[pb][n * 16 + l15][32 + g * 8]);
      f32x4 a = {};
      a = __builtin_amdgcn_mfma_f32_16x16x32_bf16(qf0, k0, a, 0, 0, 0);
      a = __builtin_amdgcn_mfma_f32_16x16x32_bf16(qf1, k1, a, 0, 0, 0);
      st[n] = a;
    }
    if (t >= 2 * qb) {  // diagonal spans the last two tiles (absolute idx)
#pragma unroll
      for (int n = 0; n < 4; ++n)
#pragma unroll
        for (int i = 0; i < 4; ++i) {
          const int s_abs = t * 64 + n * 16 + l15;
          const int q_abs = qw + 4 * g + i;
          if (s_abs > q_abs) st[n][i] = -1e30f;
        }
    }
    float pm[4];
#pragma unroll
    for (int i = 0; i < 4; ++i)
      pm[i] = fmaxf(fmaxf(st[0][i], st[1][i]), fmaxf(st[2][i], st[3][i]));
#pragma unroll
    for (int msk = 1; msk < 16; msk <<= 1)
#pragma unroll
      for (int i = 0; i < 4; ++i) pm[i] = fmaxf(pm[i], __shfl_xor(pm[i], msk));
    bool need = false;  // T13 defer-max
#pragma unroll
    for (int i = 0; i < 4; ++i) need = need || (pm[i] > mrow[i] + 12.f);
    if (__any(need)) {
#pragma unroll
      for (int i = 0; i < 4; ++i) {
        const float mnew = fmaxf(mrow[i], pm[i]);
        const float corr = exp2f((mrow[i] - mnew) * c);
        mrow[i] = mnew;
        lrow[i] *= corr;
#pragma unroll
        for (int dt = 0; dt < 4; ++dt) oacc[dt][i] *= corr;
      }
    }
    float p[4][4];
#pragma unroll
    for (int n = 0; n < 4; ++n)
#pragma unroll
      for (int i = 0; i < 4; ++i) p[n][i] = exp2f((st[n][i] - mrow[i]) * c);
#pragma unroll
    for (int i = 0; i < 4; ++i)
      lrow[i] += (p[0][i] + p[1][i]) + (p[2][i] + p[3][i]);
#pragma unroll
    for (int n = 0; n < 4; ++n)
#pragma unroll
      for (int i = 0; i < 4; ++i)
        sP[w][4 * g + i][n * 16 + l15] = f2bf(p[n][i]);
    s16x8 pf0 = *(const s16x8*)(&sP[w][l15][g * 8]);
    s16x8 pf1 = *(const s16x8*)(&sP[w][l15][32 + g * 8]);
#pragma unroll
    for (int dt = 0; dt < 4; ++dt) {
      s16x8 vf0 = ld_s16x8_a8(&sVt[pb][dt * 16 + l15][g * 8]);
      s16x8 vf1 = ld_s16x8_a8(&sVt[pb][dt * 16 + l15][32 + g * 8]);
      oacc[dt] = __builtin_amdgcn_mfma_f32_16x16x32_bf16(pf0, vf0, oacc[dt], 0, 0, 0);
      oacc[dt] = __builtin_amdgcn_mfma_f32_16x16x32_bf16(pf1, vf1, oacc[dt], 0, 0, 0);
    }
  }

#pragma unroll
  for (int msk = 1; msk < 16; msk <<= 1)
#pragma unroll
    for (int i = 0; i < 4; ++i) lrow[i] += __shfl_xor(lrow[i], msk);
  float inv[4];
#pragma unroll
  for (int i = 0; i < 4; ++i) inv[i] = 1.f / lrow[i];
#pragma unroll
  for (int dt = 0; dt < 4; ++dt)
#pragma unroll
    for (int i = 0; i < 4; ++i) {
      const size_t row = (size_t)(b * 2048 + qw + 4 * g + i);
      o[row * 1024 + h * 64 + dt * 16 + l15] = f2bf(oacc[dt][i] * inv[i]);
    }
}

// ---------------------------------------------------------------------------
extern "C" void kernel_launch(void* const* d_in, const int* in_sizes, int n_in,
                              void* d_out, int out_size, void* d_ws, size_t ws_size,
                              hipStream_t stream) {
  const float* x     = (const float*)d_in[0];
  const float* Wq    = (const float*)d_in[1];
  const float* Wk    = (const float*)d_in[2];
  const float* Wv    = (const float*)d_in[3];
  const float* Wproj = (const float*)d_in[4];
  const float* bproj = (const float*)d_in[5];
  const float* W1    = (const float*)d_in[6];
  const float* b1    = (const float*)d_in[7];
  const float* W2    = (const float*)d_in[8];
  const float* b2    = (const float*)d_in[9];
  const float* g1    = (const float*)d_in[10];
  const float* be1   = (const float*)d_in[11];
  const float* g2    = (const float*)d_in[12];
  const float* be2   = (const float*)d_in[13];
  float* out = (float*)d_out;

  u16* WqkvT  = (u16*)d_ws;                    // [3072][1024] bf16
  u16* WprojT = WqkvT + (size_t)3072 * 1024;   // [1024][1024]
  u16* W1T    = WprojT + (size_t)1024 * 1024;  // [4096][1024]
  u16* W2T    = W1T + (size_t)4096 * 1024;     // [1024][4096]
  u16* hbuf   = W2T + (size_t)1024 * 4096;     // [4096][1024]
  u16* qkv    = hbuf + (size_t)4096 * 1024;    // [4096][3072]
  u16* obuf   = qkv + (size_t)4096 * 3072;     // [4096][1024]
  float* x2   = (float*)(obuf + (size_t)4096 * 1024);  // [4096][1024] fp32
  u16* a1     = (u16*)(x2 + (size_t)4096 * 1024);      // [4096][4096]
  float* Pk   = (float*)hbuf;  // FF2 split-K partials (32 MB over hbuf+qkv)

  transpose_all_kernel<<<3072, 256, 0, stream>>>(Wq, Wk, Wv, Wproj, W1, W2,
                                                 WqkvT, WprojT, W1T, W2T);
  ln_kernel<<<4096, 256, 0, stream>>>(x, g1, be1, hbuf);
  gemm256_kernel<0><<<dim3(12, 16), 512, 0, stream>>>(hbuf, WqkvT, nullptr, nullptr, qkv, 4096, 3072, 1024);
  attn_mfma_kernel<<<512, 512, 0, stream>>>(qkv, obuf);
  gemm128d_kernel<2><<<dim3(8, 32), 256, 0, stream>>>(obuf, WprojT, bproj, x, x2, 4096, 1024, 1024, 1024);
  ln_kernel<<<4096, 256, 0, stream>>>(x2, g2, be2, hbuf);
  gemm256_kernel<1><<<dim3(16, 16), 512, 0, stream>>>(hbuf, W1T, b1, nullptr, a1, 4096, 4096, 1024);
  gemm128d_kernel<3><<<dim3(8, 32, 2), 256, 0, stream>>>(a1, W2T, nullptr, nullptr, Pk, 4096, 1024, 2048, 4096);
  combine_kernel<<<4096, 256, 0, stream>>>(Pk, x2, b2, out);
}